// Round 11
// baseline (453.190 us; speedup 1.0000x reference)
//
#include <hip/hip_runtime.h>
#include <math.h>

// ---------------------------------------------------------------------------
// N=50000 nodes, E=800000 edges (+N self-loops), IN=256, HID=128, OUT=128.
// GEMMs: bf16 MFMA 16x16x32, STAGED (glds16 + XOR swizzle), 64-row x
// 128-col tiles / 4 waves (acc 2x4).
// MLP1+MLP2+GAT1proj fused in ONE kernel; CSR scatter in its prologue.
// GAT: fused softmax+aggregation — at gather roofline (3.6 TB/s), frozen.
// CSR build: ZERO global atomics.  count_hist = (chunk x dst-range) blocks
// with LDS histograms (rank = LDS-atomic return); hierarchical prefix
// C[q][d] folded into the scan chain.  Far-atomic wall (~14G op/s flat,
// insensitive to padding/locality/overlap — R3/R5/R6) eliminated.
// ---------------------------------------------------------------------------

#define NEG_SLOPE 0.2f
#define EPS_DEN 1e-16f
#define PR 16  // dst ranges (LDS histogram width = ceil(N/PR) <= 3200)
#define QC 32  // edge chunks

typedef __attribute__((ext_vector_type(8))) short short8;
typedef __attribute__((ext_vector_type(4))) float f32x4;
typedef __attribute__((ext_vector_type(2))) float f32x2;
typedef __attribute__((ext_vector_type(4))) unsigned short u16x4;

__device__ inline unsigned short f2b(float f) {  // RNE float->bf16
  unsigned u = __builtin_bit_cast(unsigned, f);
  unsigned r = (u + 0x7fffu + ((u >> 16) & 1u)) >> 16;
  return (unsigned short)r;
}
__device__ inline float b2f(unsigned short u) {
  return __builtin_bit_cast(float, (unsigned)u << 16);
}

__device__ inline void glds16(const void* g, void* l) {
  __builtin_amdgcn_global_load_lds(
      (const __attribute__((address_space(1))) void*)g,
      (__attribute__((address_space(3))) void*)l, 16, 0, 0);
}

// packed 2xf32 fma (gfx90a+/gfx950): d = a*b + c on a VGPR pair
__device__ inline f32x2 pk_fma(f32x2 a, f32x2 b, f32x2 c) {
  f32x2 d;
  asm("v_pk_fma_f32 %0, %1, %2, %3" : "=v"(d) : "v"(a), "v"(b), "v"(c));
  return d;
}

// acc2[p] += w * bf16x8 row fragment (pairs 2p/2p+1 in lo/hi of each dword)
__device__ inline void accum8(f32x2 acc2[4], const short8 r, float w) {
  const f32x2 wv = {w, w};
  const unsigned* u = (const unsigned*)&r;
#pragma unroll
  for (int p = 0; p < 4; p++) {
    const unsigned lo = u[p] << 16;
    const unsigned hi = u[p] & 0xffff0000u;
    f32x2 val = {__builtin_bit_cast(float, lo), __builtin_bit_cast(float, hi)};
    acc2[p] = pk_fma(val, wv, acc2[p]);
  }
}

template <int H>
__device__ inline void loadH(const float* p, float* v) {
  if constexpr (H == 4) {
    float4 t = *(const float4*)p;
    v[0] = t.x; v[1] = t.y; v[2] = t.z; v[3] = t.w;
  } else if constexpr (H == 2) {
    float2 t = *(const float2*)p;
    v[0] = t.x; v[1] = t.y;
  } else {
    v[0] = *p;
  }
}

// ===========================================================================
// bf16 MFMA GEMM, staged, 64x128 tile: C[n x M] = act(A[n x K]@Bt^T + bias)
//   H>0: fused attention-logit epilogue, atomic-free.
// ===========================================================================
template <int ACT, int OBF, int H, int CC>
__global__ __launch_bounds__(256) void mfma_gemm(
    const unsigned short* __restrict__ A, const unsigned short* __restrict__ Bt,
    const float* __restrict__ bias, float* __restrict__ Cf,
    unsigned short* __restrict__ Cb, const float* __restrict__ a_s,
    const float* __restrict__ a_d, float* __restrict__ alS,
    float* __restrict__ alD, int n, int K, int M) {
  __shared__ unsigned short As[64 * 64];
  __shared__ unsigned short Bs[128 * 64];

  const int tid = threadIdx.x;
  const int w = tid >> 6, lane = tid & 63;
  const int row0 = blockIdx.x * 64, col0 = blockIdx.y * 128;
  const int lr = lane >> 3, lg = lane & 7;
  const int lm = lane & 15, kg = lane >> 4;
  const int wm = (w >> 1) * 32, wn = (w & 1) * 64;

  f32x4 acc[2][4];
#pragma unroll
  for (int i = 0; i < 2; i++)
#pragma unroll
    for (int j = 0; j < 4; j++) acc[i][j] = {0.f, 0.f, 0.f, 0.f};

  const int swz = (lg ^ lr) << 3;

  for (int k0 = 0; k0 < K; k0 += 64) {
    __syncthreads();
#pragma unroll
    for (int it = 0; it < 2; it++) {
      const int r = w * 16 + it * 8;
      glds16(A + (size_t)(row0 + r + lr) * K + k0 + swz, &As[r * 64]);
    }
#pragma unroll
    for (int it = 0; it < 4; it++) {
      const int r = w * 32 + it * 8;
      glds16(Bt + (size_t)(col0 + r + lr) * K + k0 + swz, &Bs[r * 64]);
    }
    __syncthreads();

#pragma unroll
    for (int kh = 0; kh < 2; kh++) {
      const int sw = ((kh * 4 + kg) ^ (lm & 7)) << 3;
      short8 aF[2], bF[4];
#pragma unroll
      for (int i = 0; i < 2; i++)
        aF[i] = *(const short8*)&As[(wm + i * 16 + lm) * 64 + sw];
#pragma unroll
      for (int j = 0; j < 4; j++)
        bF[j] = *(const short8*)&Bs[(wn + j * 16 + lm) * 64 + sw];
#pragma unroll
      for (int i = 0; i < 2; i++)
#pragma unroll
        for (int j = 0; j < 4; j++)
          acc[i][j] = __builtin_amdgcn_mfma_f32_16x16x32_bf16(
              aF[i], bF[j], acc[i][j], 0, 0, 0);
    }
  }

  const int r4 = kg * 4;

  // ---- fused alpha epilogue (pre-activation, pre-bias projection) ----
  if constexpr (H > 0) {
    const int head = (col0 + wn) / CC;
    const int ch0 = (col0 + wn) % CC;
    float asv[4], adv[4];
#pragma unroll
    for (int j = 0; j < 4; j++) {
      asv[j] = a_s[head * CC + ch0 + j * 16 + lm];
      adv[j] = a_d[head * CC + ch0 + j * 16 + lm];
    }
    float psA[2][4], pdA[2][4];
#pragma unroll
    for (int i = 0; i < 2; i++) {
#pragma unroll
      for (int r = 0; r < 4; r++) {
        float ps = 0.f, pd = 0.f;
#pragma unroll
        for (int j = 0; j < 4; j++) {
          ps += acc[i][j][r] * asv[j];
          pd += acc[i][j][r] * adv[j];
        }
#pragma unroll
        for (int off = 1; off < 16; off <<= 1) {
          ps += __shfl_xor(ps, off, 64);
          pd += __shfl_xor(pd, off, 64);
        }
        psA[i][r] = ps;
        pdA[i][r] = pd;
      }
    }
    if constexpr (CC == 64) {
      if (lm == 0) {
#pragma unroll
        for (int i = 0; i < 2; i++)
#pragma unroll
          for (int r = 0; r < 4; r++) {
            const int row = row0 + wm + i * 16 + r4 + r;
            if (row < n) {
              alS[(size_t)row * H + head] = psA[i][r];
              alD[(size_t)row * H + head] = pdA[i][r];
            }
          }
      }
    } else {
      // CC==128: waves w and w^1 cover the same rows (wn=0/64, same wm)
      __shared__ float redS[4][32];
      __shared__ float redD[4][32];
      if (lm == 0) {
#pragma unroll
        for (int i = 0; i < 2; i++)
#pragma unroll
          for (int r = 0; r < 4; r++) {
            redS[w][i * 16 + r4 + r] = psA[i][r];
            redD[w][i * 16 + r4 + r] = pdA[i][r];
          }
      }
      __syncthreads();
      if ((w & 1) == 0 && lane < 32) {
        const int row = row0 + wm + lane;
        if (row < n) {
          const int hd = col0 / CC;
          alS[(size_t)row * H + hd] = redS[w][lane] + redS[w + 1][lane];
          alD[(size_t)row * H + hd] = redD[w][lane] + redD[w + 1][lane];
        }
      }
    }
  }

#pragma unroll
  for (int j = 0; j < 4; j++) {
    const int col = col0 + wn + j * 16 + lm;
    const float bv = bias ? bias[col] : 0.f;
#pragma unroll
    for (int i = 0; i < 2; i++) {
#pragma unroll
      for (int r = 0; r < 4; r++) {
        const int row = row0 + wm + i * 16 + r4 + r;
        if (row < n) {
          float v = acc[i][j][r] + bv;
          if (ACT == 1) v = v > 0.f ? v : 0.f;
          if (OBF)
            Cb[(size_t)row * M + col] = f2b(v);
          else
            Cf[(size_t)row * M + col] = v;
        }
      }
    }
  }
}

// ===========================================================================
// Fused MLP + GAT1 projection, staged, 64-row tile, WITH CSR-scatter
// prologue (pos = rowptr[d] + Cpref[q][d] + rank[i], zero atomics).
// ===========================================================================
__global__ __launch_bounds__(256) void mlp_g1_kernel(
    const unsigned short* __restrict__ X, const unsigned short* __restrict__ W1t,
    const float* __restrict__ b1, const unsigned short* __restrict__ W2t,
    const float* __restrict__ b2, const unsigned short* __restrict__ G1Wt,
    const float* __restrict__ a_s, const float* __restrict__ a_d,
    float* __restrict__ alS, float* __restrict__ alD,
    unsigned short* __restrict__ Pb,
    const int* __restrict__ esrc, const int* __restrict__ edst,
    const int* __restrict__ rank, const int* __restrict__ rowptr,
    const int* __restrict__ Cpref, int* __restrict__ csr_src, int E, int n) {
  __shared__ unsigned short As[64 * 64];
  __shared__ unsigned short Bs[128 * 64];
  __shared__ unsigned short H1s[64 * 136];

  const int tid = threadIdx.x;
  const int w = tid >> 6, lane = tid & 63;
  const int row0 = blockIdx.x * 64;
  const int lr = lane >> 3, lg = lane & 7;
  const int lm = lane & 15, kg = lane >> 4;
  const int wm = (w >> 1) * 32, wn = (w & 1) * 64;
  const int swz = (lg ^ lr) << 3;
  const int r4 = kg * 4;

  // ---- prologue: atomic-free CSR scatter ----
  {
    const int tot = E + n;
    const int CS = (tot + QC - 1) / QC;
    const int gsz = (int)gridDim.x * 256;
    for (int i = (int)blockIdx.x * 256 + tid; i < tot; i += gsz) {
      int s, d;
      if (i < E) {
        s = __builtin_nontemporal_load(esrc + i);
        d = __builtin_nontemporal_load(edst + i);
      } else {
        s = d = i - E;
      }
      if ((unsigned)d < (unsigned)n && (unsigned)s < (unsigned)n) {
        const int q = i / CS;
        const int pos = rowptr[d] + Cpref[(size_t)q * n + d] +
                        __builtin_nontemporal_load(rank + i);
        __builtin_nontemporal_store(s, csr_src + pos);
      }
    }
  }

  f32x4 acc[2][4];
#pragma unroll
  for (int i = 0; i < 2; i++)
#pragma unroll
    for (int j = 0; j < 4; j++) acc[i][j] = {0.f, 0.f, 0.f, 0.f};

  // ---- phase A: h1 = relu(x @ W1t^T + b1), K=256, M=128 ----
  for (int k0 = 0; k0 < 256; k0 += 64) {
    __syncthreads();
#pragma unroll
    for (int it = 0; it < 2; it++) {
      const int r = w * 16 + it * 8;
      glds16(X + (size_t)(row0 + r + lr) * 256 + k0 + swz, &As[r * 64]);
    }
#pragma unroll
    for (int it = 0; it < 4; it++) {
      const int r = w * 32 + it * 8;
      glds16(W1t + (size_t)(r + lr) * 256 + k0 + swz, &Bs[r * 64]);
    }
    __syncthreads();
#pragma unroll
    for (int kh = 0; kh < 2; kh++) {
      const int sw = ((kh * 4 + kg) ^ (lm & 7)) << 3;
      short8 aF[2], bF[4];
#pragma unroll
      for (int i = 0; i < 2; i++)
        aF[i] = *(const short8*)&As[(wm + i * 16 + lm) * 64 + sw];
#pragma unroll
      for (int j = 0; j < 4; j++)
        bF[j] = *(const short8*)&Bs[(wn + j * 16 + lm) * 64 + sw];
#pragma unroll
      for (int i = 0; i < 2; i++)
#pragma unroll
        for (int j = 0; j < 4; j++)
          acc[i][j] = __builtin_amdgcn_mfma_f32_16x16x32_bf16(
              aF[i], bF[j], acc[i][j], 0, 0, 0);
    }
  }

  // epilogue A -> LDS (bias + relu, bf16)
#pragma unroll
  for (int j = 0; j < 4; j++) {
    const int col = wn + j * 16 + lm;
    const float bv = b1[col];
#pragma unroll
    for (int i = 0; i < 2; i++) {
#pragma unroll
      for (int r = 0; r < 4; r++) {
        const int lrow = wm + i * 16 + r4 + r;
        float v = acc[i][j][r] + bv;
        v = v > 0.f ? v : 0.f;
        H1s[lrow * 136 + col] = f2b(v);
      }
    }
  }
#pragma unroll
  for (int i = 0; i < 2; i++)
#pragma unroll
    for (int j = 0; j < 4; j++) acc[i][j] = {0.f, 0.f, 0.f, 0.f};
  __syncthreads();  // H1s complete before phase B reads

  // ---- phase B: h2 = relu(h1 @ W2t^T + b2), K=128, M=128 ----
  for (int k0 = 0; k0 < 128; k0 += 64) {
    __syncthreads();  // protect Bs reuse
#pragma unroll
    for (int it = 0; it < 4; it++) {
      const int r = w * 32 + it * 8;
      glds16(W2t + (size_t)(r + lr) * 128 + k0 + swz, &Bs[r * 64]);
    }
    __syncthreads();
#pragma unroll
    for (int kh = 0; kh < 2; kh++) {
      const int swB = ((kh * 4 + kg) ^ (lm & 7)) << 3;
      const int kofs = k0 + (kh * 4 + kg) * 8;
      short8 aF[2], bF[4];
#pragma unroll
      for (int i = 0; i < 2; i++)
        aF[i] = *(const short8*)&H1s[(wm + i * 16 + lm) * 136 + kofs];
#pragma unroll
      for (int j = 0; j < 4; j++)
        bF[j] = *(const short8*)&Bs[(wn + j * 16 + lm) * 64 + swB];
#pragma unroll
      for (int i = 0; i < 2; i++)
#pragma unroll
        for (int j = 0; j < 4; j++)
          acc[i][j] = __builtin_amdgcn_mfma_f32_16x16x32_bf16(
              aF[i], bF[j], acc[i][j], 0, 0, 0);
    }
  }

  // epilogue B: h2 (bias+relu, bf16) back into H1s (all reads done)
  __syncthreads();
#pragma unroll
  for (int j = 0; j < 4; j++) {
    const int col = wn + j * 16 + lm;
    const float bv = b2[col];
#pragma unroll
    for (int i = 0; i < 2; i++) {
#pragma unroll
      for (int r = 0; r < 4; r++) {
        const int lrow = wm + i * 16 + r4 + r;
        float v = acc[i][j][r] + bv;
        v = v > 0.f ? v : 0.f;
        H1s[lrow * 136 + col] = f2b(v);
      }
    }
  }
  __syncthreads();  // h2 complete before phase C reads

  // ---- phase C: P = h2 @ G1Wt^T, K=128, M=256 (2 col-halves) ----
  for (int c = 0; c < 2; c++) {
#pragma unroll
    for (int i = 0; i < 2; i++)
#pragma unroll
      for (int j = 0; j < 4; j++) acc[i][j] = {0.f, 0.f, 0.f, 0.f};

    for (int k0 = 0; k0 < 128; k0 += 64) {
      __syncthreads();  // protect Bs reuse
#pragma unroll
      for (int it = 0; it < 4; it++) {
        const int r = w * 32 + it * 8;
        glds16(G1Wt + (size_t)(c * 128 + r + lr) * 128 + k0 + swz,
               &Bs[r * 64]);
      }
      __syncthreads();
#pragma unroll
      for (int kh = 0; kh < 2; kh++) {
        const int swB = ((kh * 4 + kg) ^ (lm & 7)) << 3;
        const int kofs = k0 + (kh * 4 + kg) * 8;
        short8 aF[2], bF[4];
#pragma unroll
        for (int i = 0; i < 2; i++)
          aF[i] = *(const short8*)&H1s[(wm + i * 16 + lm) * 136 + kofs];
#pragma unroll
        for (int j = 0; j < 4; j++)
          bF[j] = *(const short8*)&Bs[(wn + j * 16 + lm) * 64 + swB];
#pragma unroll
        for (int i = 0; i < 2; i++)
#pragma unroll
          for (int j = 0; j < 4; j++)
            acc[i][j] = __builtin_amdgcn_mfma_f32_16x16x32_bf16(
                aF[i], bF[j], acc[i][j], 0, 0, 0);
      }
    }

    // GAT1 alpha epilogue: H=4, CC=64.  head = 2c + wn/64, unique writer.
    {
      const int head = c * 2 + (wn >> 6);
      float asv[4], adv[4];
#pragma unroll
      for (int j = 0; j < 4; j++) {
        asv[j] = a_s[head * 64 + j * 16 + lm];
        adv[j] = a_d[head * 64 + j * 16 + lm];
      }
#pragma unroll
      for (int i = 0; i < 2; i++) {
#pragma unroll
        for (int r = 0; r < 4; r++) {
          float ps = 0.f, pd = 0.f;
#pragma unroll
          for (int j = 0; j < 4; j++) {
            ps += acc[i][j][r] * asv[j];
            pd += acc[i][j][r] * adv[j];
          }
#pragma unroll
          for (int off = 1; off < 16; off <<= 1) {
            ps += __shfl_xor(ps, off, 64);
            pd += __shfl_xor(pd, off, 64);
          }
          if (lm == 0) {
            const int row = row0 + wm + i * 16 + r4 + r;
            if (row < n) {
              alS[(size_t)row * 4 + head] = ps;
              alD[(size_t)row * 4 + head] = pd;
            }
          }
        }
      }
    }

    // C-write -> Pb (bf16, no bias, no activation)
#pragma unroll
    for (int j = 0; j < 4; j++) {
      const int col = c * 128 + wn + j * 16 + lm;
#pragma unroll
      for (int i = 0; i < 2; i++) {
#pragma unroll
        for (int r = 0; r < 4; r++) {
          const int row = row0 + wm + i * 16 + r4 + r;
          if (row < n) Pb[(size_t)row * 256 + col] = f2b(acc[i][j][r]);
        }
      }
    }
  }
}

// ===========================================================================
// Fused head prep: convert x fp32->bf16 + 5 weight transposes.  Pure
// streaming (edge counting moved to count_hist; zero atomics here).
// ===========================================================================
struct PrepArgs {
  const float* x; unsigned short* xb; long long nx;
  const float* W[5]; unsigned short* Wt[5];
  int K[5], M[5], t0[6];
};

__global__ __launch_bounds__(256) void fused_prep_kernel(PrepArgs a) {
  const int tid = threadIdx.x, bid = blockIdx.x, nb = gridDim.x;
  const long long gt = (long long)bid * 256 + tid;
  const long long gsz = (long long)nb * 256;
  __shared__ float tt[32][33];

  for (long long i = gt * 4; i < a.nx; i += gsz * 4) {
    float4 v = *(const float4*)(a.x + i);
    u16x4 u = {f2b(v.x), f2b(v.y), f2b(v.z), f2b(v.w)};
    *(u16x4*)(a.xb + i) = u;
  }
  for (int t = bid; t < a.t0[5]; t += nb) {
    int di = 0;
    while (t >= a.t0[di + 1]) di++;
    const int local = t - a.t0[di];
    const int K = a.K[di], M = a.M[di], mtiles = M / 32;
    const int mb = (local % mtiles) * 32, kb = (local / mtiles) * 32;
    const float* W = a.W[di];
    unsigned short* Wt = a.Wt[di];
    const int tx = tid & 31, ty = tid >> 5;  // 32 x 8
    __syncthreads();
#pragma unroll
    for (int i = 0; i < 4; i++)
      tt[ty + i * 8][tx] = W[(size_t)(kb + ty + i * 8) * M + mb + tx];
    __syncthreads();
#pragma unroll
    for (int i = 0; i < 4; i++)
      Wt[(size_t)(mb + ty + i * 8) * K + kb + tx] = f2b(tt[tx][ty + i * 8]);
  }
}

// ===========================================================================
// CSR build pass 1: LDS-histogram count + rank capture.  ZERO global
// atomics.  Block (q,p): scan edge chunk q, histogram dsts in range p into
// LDS; rank[i] = LDS-atomic return; dump histogram to C[q][range].
// ===========================================================================
__global__ __launch_bounds__(256) void count_hist_kernel(
    const int* __restrict__ edst, int* __restrict__ rank,
    int* __restrict__ C, int E, int n) {
  __shared__ int h[3200];  // ceil(50000/16)=3125
  const int tid = threadIdx.x;
  const int q = blockIdx.x, p = blockIdx.y;
  const int RANGE = (n + PR - 1) / PR;
  const int lo = p * RANGE;

  for (int i = tid; i < RANGE; i += 256) h[i] = 0;
  __syncthreads();

  const int tot = E + n;
  const int CS = (tot + QC - 1) / QC;
  const int start = q * CS;
  const int end = min(start + CS, tot);
  for (int i = start + tid; i < end; i += 256) {
    int d = (i < E) ? __builtin_nontemporal_load(edst + i) : (i - E);
    const int r = d - lo;
    if ((unsigned)r < (unsigned)RANGE && d < n)
      __builtin_nontemporal_store(atomicAdd(&h[r], 1), rank + i);
  }
  __syncthreads();

  for (int i = tid; i < RANGE; i += 256)
    if (lo + i < n) C[(size_t)q * n + lo + i] = h[i];
}

// ===========================================================================
// CSR scan chain.  deg = sum_q C[q][d]; scan_final also converts C[q][d]
// to exclusive prefix over q in place.
// ===========================================================================
__global__ __launch_bounds__(256) void block_reduce_kernel(
    const int* __restrict__ C, int* __restrict__ deg, int* __restrict__ bsum,
    int n) {
  __shared__ int s[256];
  const int t = threadIdx.x, i = blockIdx.x * 256 + t;
  int v = 0;
  if (i < n) {
#pragma unroll
    for (int q = 0; q < QC; q++) v += C[(size_t)q * n + i];
    deg[i] = v;
  }
  s[t] = v;
  __syncthreads();
#pragma unroll
  for (int off = 128; off; off >>= 1) {
    if (t < off) s[t] += s[t + off];
    __syncthreads();
  }
  if (t == 0) bsum[blockIdx.x] = s[0];
}

__global__ __launch_bounds__(256) void scan_bsums_kernel(int* __restrict__ bsum,
                                                         int nb) {
  __shared__ int s[256];
  const int t = threadIdx.x;
  const int v = (t < nb) ? bsum[t] : 0;
  s[t] = v;
  __syncthreads();
#pragma unroll
  for (int off = 1; off < 256; off <<= 1) {
    int a = (t >= off) ? s[t - off] : 0;
    __syncthreads();
    s[t] += a;
    __syncthreads();
  }
  if (t < nb) bsum[t] = s[t] - v;
}

__global__ __launch_bounds__(256) void scan_final_kernel(
    const int* __restrict__ deg, int* __restrict__ C,
    const int* __restrict__ bsumx, int* __restrict__ rowptr, int n) {
  __shared__ int s[256];
  const int t = threadIdx.x, i = blockIdx.x * 256 + t;
  const int v = (i < n) ? deg[i] : 0;
  s[t] = v;
  __syncthreads();
#pragma unroll
  for (int off = 1; off < 256; off <<= 1) {
    int a = (t >= off) ? s[t - off] : 0;
    __syncthreads();
    s[t] += a;
    __syncthreads();
  }
  if (i < n) {
    const int base = bsumx[blockIdx.x];
    rowptr[i] = base + s[t] - v;
    if (i == n - 1) rowptr[n] = base + s[t];
    int run = 0;
#pragma unroll
    for (int q = 0; q < QC; q++) {
      const int c = C[(size_t)q * n + i];
      C[(size_t)q * n + i] = run;
      run += c;
    }
  }
}

// ===========================================================================
// FUSED GAT softmax + aggregation.  Wave per dst.  AT gather roofline —
// do not touch.
// ===========================================================================
template <int H, int C, bool CONCAT, int ACT, int OBF>
__global__ __launch_bounds__(256) void gat_fused_kernel(
    const unsigned short* __restrict__ proj, const float* __restrict__ alpha_s,
    const float* __restrict__ alpha_d, const int* __restrict__ rowptr,
    const int* __restrict__ csr_src, const float* __restrict__ bias,
    void* __restrict__ out, int n) {
  constexpr int HC = H * C;
  constexpr int ROWSPAN = HC / 8;      // lanes covering one row (16 or 32)
  constexpr int EDGES = 64 / ROWSPAN;  // edges in flight (2 or 4)
  constexpr int WLANES = C / 8;        // writer lanes in mean mode

  __shared__ float exs[4][64 * H];
  __shared__ int sids[4][64];

  const int wv = threadIdx.x >> 6;
  const int wid = (blockIdx.x * blockDim.x + threadIdx.x) >> 6;
  const int lane = threadIdx.x & 63;
  if (wid >= n) return;
  const int dst = wid;
  const int eslot = lane / ROWSPAN;
  const int sl = lane % ROWSPAN;    // row slice: flat channels sl*8..sl*8+7
  const int h_lane = (sl * 8) / C;  // head owning this slice
  float* myex = &exs[wv][0];
  int* mysid = &sids[wv][0];

  float adv[H];
  loadH<H>(alpha_d + (size_t)dst * H, adv);
  const int rs = rowptr[dst], re = rowptr[dst + 1];

  float denomp[H];
#pragma unroll
  for (int h = 0; h < H; h++) denomp[h] = 0.f;
  f32x2 acc2[4];
#pragma unroll
  for (int p = 0; p < 4; p++) acc2[p] = {0.f, 0.f};

  const unsigned short* prow = proj + sl * 8;

  for (int base = rs; base < re; base += 64) {
    const int cnt = min(64, re - base);
    // phase 1: lane-parallel edge weights + src ids -> LDS
    if (lane < cnt) {
      const int s = __builtin_nontemporal_load(csr_src + base + lane);
      mysid[lane] = s;
      float as[H];
      loadH<H>(alpha_s + (size_t)s * H, as);
#pragma unroll
      for (int h = 0; h < H; h++) {
        float e = as[h] + adv[h];
        e = e > 0.f ? e : NEG_SLOPE * e;
        const float ex = __expf(e);
        denomp[h] += ex;
        myex[lane * H + h] = ex;
      }
    }
    __builtin_amdgcn_wave_barrier();
    // phase 2: subgroup-parallel accumulation, unrolled x2
    int j = eslot;
    for (; j + EDGES < cnt; j += 2 * EDGES) {
      const int s0 = mysid[j];
      const int s1 = mysid[j + EDGES];
      const float w0 = myex[j * H + h_lane];
      const float w1 = myex[(j + EDGES) * H + h_lane];
      const short8 r0 = *(const short8*)(prow + (size_t)s0 * HC);
      const short8 r1 = *(const short8*)(prow + (size_t)s1 * HC);
      accum8(acc2, r0, w0);
      accum8(acc2, r1, w1);
    }
    for (; j < cnt; j += EDGES) {
      const int s0 = mysid[j];
      const float w0 = myex[j * H + h_lane];
      const short8 r0 = *(const short8*)(prow + (size_t)s0 * HC);
      accum8(acc2, r0, w0);
    }
    __builtin_amdgcn_wave_barrier();
  }

  // unpack packed accumulators
  float acc[8];
#pragma unroll
  for (int p = 0; p < 4; p++) {
    acc[2 * p] = acc2[p].x;
    acc[2 * p + 1] = acc2[p].y;
  }

  // full-wave denom reduce; edge-slot acc reduce
#pragma unroll
  for (int off = 32; off; off >>= 1)
#pragma unroll
    for (int h = 0; h < H; h++)
      denomp[h] += __shfl_xor(denomp[h], off, 64);
#pragma unroll
  for (int off = ROWSPAN; off < 64; off <<= 1)
#pragma unroll
    for (int k = 0; k < 8; k++) acc[k] += __shfl_xor(acc[k], off, 64);

  const float inv = 1.f / (denomp[h_lane] + EPS_DEN);
  float v[8];
#pragma unroll
  for (int k = 0; k < 8; k++) v[k] = acc[k] * inv;

  if (!CONCAT && H == 2) {
#pragma unroll
    for (int k = 0; k < 8; k++) v[k] += __shfl_xor(v[k], 16, 64);
  }

  if (CONCAT) {
    if (eslot != 0) return;
    const int c0 = sl * 8;
    float vv[8];
#pragma unroll
    for (int k = 0; k < 8; k++) {
      float t = v[k] + bias[c0 + k];
      if (ACT == 1) t = t > 0.f ? t : (__expf(t) - 1.f);
      vv[k] = t;
    }
    if (OBF) {
      short8 o;
#pragma unroll
      for (int k = 0; k < 8; k++) o[k] = (short)f2b(vv[k]);
      __builtin_nontemporal_store(
          o, (short8*)((unsigned short*)out + (size_t)dst * HC + c0));
    } else {
      float* op = (float*)out + (size_t)dst * HC + c0;
      f32x4 o0 = {vv[0], vv[1], vv[2], vv[3]};
      f32x4 o1 = {vv[4], vv[5], vv[6], vv[7]};
      __builtin_nontemporal_store(o0, (f32x4*)op);
      __builtin_nontemporal_store(o1, (f32x4*)(op + 4));
    }
  } else {
    if (eslot != 0 || sl >= WLANES) return;
    const int c0 = sl * 8;
    const float invH = 1.f / (float)H;
    float vv[8];
#pragma unroll
    for (int k = 0; k < 8; k++) {
      float t = v[k] * invH + bias[c0 + k];
      if (ACT == 1) t = t > 0.f ? t : (__expf(t) - 1.f);
      vv[k] = t;
    }
    if (OBF) {
      short8 o;
#pragma unroll
      for (int k = 0; k < 8; k++) o[k] = (short)f2b(vv[k]);
      __builtin_nontemporal_store(
          o, (short8*)((unsigned short*)out + (size_t)dst * C + c0));
    } else {
      float* op = (float*)out + (size_t)dst * C + c0;
      f32x4 o0 = {vv[0], vv[1], vv[2], vv[3]};
      f32x4 o1 = {vv[4], vv[5], vv[6], vv[7]};
      __builtin_nontemporal_store(o0, (f32x4*)op);
      __builtin_nontemporal_store(o1, (f32x4*)(op + 4));
    }
  }
}

// ===========================================================================
// Host side
// ===========================================================================
extern "C" void kernel_launch(void* const* d_in, const int* in_sizes, int n_in,
                              void* d_out, int out_size, void* d_ws,
                              size_t ws_size, hipStream_t stream) {
  const float* x    = (const float*)d_in[0];
  const int*   ei   = (const int*)d_in[1];
  const float* W1   = (const float*)d_in[2];
  const float* b1   = (const float*)d_in[3];
  const float* W2   = (const float*)d_in[4];
  const float* b2   = (const float*)d_in[5];
  const float* g1W  = (const float*)d_in[6];
  const float* g1as = (const float*)d_in[7];
  const float* g1ad = (const float*)d_in[8];
  const float* g1b  = (const float*)d_in[9];
  const float* g2W  = (const float*)d_in[10];
  const float* g2as = (const float*)d_in[11];
  const float* g2ad = (const float*)d_in[12];
  const float* g2b  = (const float*)d_in[13];
  const float* g3W  = (const float*)d_in[14];
  const float* g3as = (const float*)d_in[15];
  const float* g3ad = (const float*)d_in[16];
  const float* g3b  = (const float*)d_in[17];

  const int N = in_sizes[0] / 256;   // 50000
  const int E = in_sizes[1] / 2;     // 800000
  const int Etot = E + N;
  const int NT = (N + 127) / 128;
  const int NT64 = (N + 63) / 64;
  const int NP = NT * 128;
  const int NB = (N + 255) / 256;    // scan chunks (196 <= 256)

  // ---- workspace layout ----
  char* p = (char*)d_ws;
  unsigned short* Pb  = (unsigned short*)p; p += (size_t)NP * 256 * 2;  // bf16 proj
  unsigned short* xb  = (unsigned short*)p; p += (size_t)NP * 256 * 2;  // x / act1b
  unsigned short* h2b = (unsigned short*)p; p += (size_t)NP * 128 * 2;  // act2b
  unsigned short* W1t = (unsigned short*)p; p += (size_t)128 * 256 * 2;
  unsigned short* W2t = (unsigned short*)p; p += (size_t)128 * 128 * 2;
  unsigned short* g1Wt = (unsigned short*)p; p += (size_t)256 * 128 * 2;
  unsigned short* g2Wt = (unsigned short*)p; p += (size_t)256 * 256 * 2;
  unsigned short* g3Wt = (unsigned short*)p; p += (size_t)128 * 128 * 2;
  // alpha buffers: 3 layer pairs (fully overwritten by GEMM epilogues)
  float* alB = (float*)p; p += (size_t)N * 14 * 4;
  float* alS1 = alB;
  float* alD1 = alB + (size_t)4 * N;
  float* alS2 = alB + (size_t)8 * N;
  float* alD2 = alB + (size_t)10 * N;
  float* alS3 = alB + (size_t)12 * N;
  float* alD3 = alB + (size_t)13 * N;
  int* deg    = (int*)p; p += (size_t)N * 4;
  int* rowptr = (int*)p; p += (size_t)(N + 1) * 4;
  int* bsum   = (int*)p; p += 256 * 4;
  int* rank   = (int*)p; p += (size_t)Etot * 4;
  int* Chist  = (int*)p; p += (size_t)QC * N * 4;  // per-chunk histograms
  int* csrsrc = (int*)p;

  const int* esrc = ei;
  const int* edst = ei + E;
  unsigned short* act1b = xb;   // reuse after MLP consumed xb
  unsigned short* act2b = h2b;

  // ---- CSR pass 1 (zero atomics) + prep (streaming) ----
  count_hist_kernel<<<dim3(QC, PR), 256, 0, stream>>>(edst, rank, Chist, E, N);

  PrepArgs pa;
  pa.x = x; pa.xb = xb; pa.nx = (long long)N * 256;
  pa.W[0] = W1;  pa.Wt[0] = W1t;  pa.K[0] = 256; pa.M[0] = 128;
  pa.W[1] = W2;  pa.Wt[1] = W2t;  pa.K[1] = 128; pa.M[1] = 128;
  pa.W[2] = g1W; pa.Wt[2] = g1Wt; pa.K[2] = 128; pa.M[2] = 256;
  pa.W[3] = g2W; pa.Wt[3] = g2Wt; pa.K[3] = 256; pa.M[3] = 256;
  pa.W[4] = g3W; pa.Wt[4] = g3Wt; pa.K[4] = 128; pa.M[4] = 128;
  pa.t0[0] = 0;
  for (int i = 0; i < 5; i++)
    pa.t0[i + 1] = pa.t0[i] + (pa.K[i] / 32) * (pa.M[i] / 32);
  fused_prep_kernel<<<2048, 256, 0, stream>>>(pa);

  block_reduce_kernel<<<NB, 256, 0, stream>>>(Chist, deg, bsum, N);
  scan_bsums_kernel<<<1, 256, 0, stream>>>(bsum, NB);
  scan_final_kernel<<<NB, 256, 0, stream>>>(deg, Chist, bsum, rowptr, N);

  // ---- fused MLP + GAT1 projection + alpha + CSR scatter (one kernel) ----
  mlp_g1_kernel<<<NT64, 256, 0, stream>>>(xb, W1t, b1, W2t, b2, g1Wt, g1as,
                                          g1ad, alS1, alD1, Pb, esrc, edst,
                                          rank, rowptr, Chist, csrsrc, E, N);

  // ---- GAT1 aggregation: 4 x 64, concat, ELU ----
  gat_fused_kernel<4, 64, true, 1, 1><<<(N + 3) / 4, 256, 0, stream>>>(
      Pb, alS1, alD1, rowptr, csrsrc, g1b, act1b, N);

  // ---- GAT2: 256 -> 2 x 128, mean, ELU ----
  mfma_gemm<0, 1, 2, 128><<<dim3(NT64, 2), 256, 0, stream>>>(
      act1b, g2Wt, nullptr, nullptr, Pb, g2as, g2ad, alS2, alD2, N, 256, 256);
  gat_fused_kernel<2, 128, false, 1, 1><<<(N + 3) / 4, 256, 0, stream>>>(
      Pb, alS2, alD2, rowptr, csrsrc, g2b, act2b, N);

  // ---- GAT3: 128 -> 1 x 128, mean, none -> d_out (fp32) ----
  mfma_gemm<0, 1, 1, 128><<<dim3(NT64, 1), 256, 0, stream>>>(
      act2b, g3Wt, nullptr, nullptr, Pb, g3as, g3ad, alS3, alD3, N, 128, 128);
  gat_fused_kernel<1, 128, false, 0, 0><<<(N + 3) / 4, 256, 0, stream>>>(
      Pb, alS3, alD3, rowptr, csrsrc, g3b, d_out, N);
}

// Round 12
// 441.263 us; speedup vs baseline: 1.0270x; 1.0270x over previous
//
#include <hip/hip_runtime.h>
#include <math.h>

// ---------------------------------------------------------------------------
// N=50000 nodes, E=800000 edges (+N self-loops), IN=256, HID=128, OUT=128.
// GEMMs: bf16 MFMA 16x16x32, STAGED (glds16 + XOR swizzle), 64-row x
// 128-col tiles / 4 waves (acc 2x4).
// MLP1+MLP2+GAT1proj fused in ONE kernel; CSR scatter in its prologue.
// GAT: fused softmax+aggregation — at gather roofline (3.6 TB/s), frozen.
// CSR build: ZERO global atomics, ZERO false sharing.  count_hist = one
// block per edge chunk, full-N histogram packed 2x16-bit in 100KB LDS
// (rank = LDS-atomic return half); rank writes DENSE+coalesced per block.
// Hierarchical prefix C[q][d] folded into the scan chain.
// ---------------------------------------------------------------------------

#define NEG_SLOPE 0.2f
#define EPS_DEN 1e-16f
#define QC 64     // edge chunks (= count_hist blocks); counts/half < 2^16
#define HALFN 25000  // ceil(50000/2) LDS words

typedef __attribute__((ext_vector_type(8))) short short8;
typedef __attribute__((ext_vector_type(4))) float f32x4;
typedef __attribute__((ext_vector_type(2))) float f32x2;
typedef __attribute__((ext_vector_type(4))) unsigned short u16x4;

__device__ inline unsigned short f2b(float f) {  // RNE float->bf16
  unsigned u = __builtin_bit_cast(unsigned, f);
  unsigned r = (u + 0x7fffu + ((u >> 16) & 1u)) >> 16;
  return (unsigned short)r;
}
__device__ inline float b2f(unsigned short u) {
  return __builtin_bit_cast(float, (unsigned)u << 16);
}

__device__ inline void glds16(const void* g, void* l) {
  __builtin_amdgcn_global_load_lds(
      (const __attribute__((address_space(1))) void*)g,
      (__attribute__((address_space(3))) void*)l, 16, 0, 0);
}

// packed 2xf32 fma (gfx90a+/gfx950): d = a*b + c on a VGPR pair
__device__ inline f32x2 pk_fma(f32x2 a, f32x2 b, f32x2 c) {
  f32x2 d;
  asm("v_pk_fma_f32 %0, %1, %2, %3" : "=v"(d) : "v"(a), "v"(b), "v"(c));
  return d;
}

// acc2[p] += w * bf16x8 row fragment (pairs 2p/2p+1 in lo/hi of each dword)
__device__ inline void accum8(f32x2 acc2[4], const short8 r, float w) {
  const f32x2 wv = {w, w};
  const unsigned* u = (const unsigned*)&r;
#pragma unroll
  for (int p = 0; p < 4; p++) {
    const unsigned lo = u[p] << 16;
    const unsigned hi = u[p] & 0xffff0000u;
    f32x2 val = {__builtin_bit_cast(float, lo), __builtin_bit_cast(float, hi)};
    acc2[p] = pk_fma(val, wv, acc2[p]);
  }
}

template <int H>
__device__ inline void loadH(const float* p, float* v) {
  if constexpr (H == 4) {
    float4 t = *(const float4*)p;
    v[0] = t.x; v[1] = t.y; v[2] = t.z; v[3] = t.w;
  } else if constexpr (H == 2) {
    float2 t = *(const float2*)p;
    v[0] = t.x; v[1] = t.y;
  } else {
    v[0] = *p;
  }
}

// ===========================================================================
// bf16 MFMA GEMM, staged, 64x128 tile: C[n x M] = act(A[n x K]@Bt^T + bias)
//   H>0: fused attention-logit epilogue, atomic-free.
// ===========================================================================
template <int ACT, int OBF, int H, int CC>
__global__ __launch_bounds__(256) void mfma_gemm(
    const unsigned short* __restrict__ A, const unsigned short* __restrict__ Bt,
    const float* __restrict__ bias, float* __restrict__ Cf,
    unsigned short* __restrict__ Cb, const float* __restrict__ a_s,
    const float* __restrict__ a_d, float* __restrict__ alS,
    float* __restrict__ alD, int n, int K, int M) {
  __shared__ unsigned short As[64 * 64];
  __shared__ unsigned short Bs[128 * 64];

  const int tid = threadIdx.x;
  const int w = tid >> 6, lane = tid & 63;
  const int row0 = blockIdx.x * 64, col0 = blockIdx.y * 128;
  const int lr = lane >> 3, lg = lane & 7;
  const int lm = lane & 15, kg = lane >> 4;
  const int wm = (w >> 1) * 32, wn = (w & 1) * 64;

  f32x4 acc[2][4];
#pragma unroll
  for (int i = 0; i < 2; i++)
#pragma unroll
    for (int j = 0; j < 4; j++) acc[i][j] = {0.f, 0.f, 0.f, 0.f};

  const int swz = (lg ^ lr) << 3;

  for (int k0 = 0; k0 < K; k0 += 64) {
    __syncthreads();
#pragma unroll
    for (int it = 0; it < 2; it++) {
      const int r = w * 16 + it * 8;
      glds16(A + (size_t)(row0 + r + lr) * K + k0 + swz, &As[r * 64]);
    }
#pragma unroll
    for (int it = 0; it < 4; it++) {
      const int r = w * 32 + it * 8;
      glds16(Bt + (size_t)(col0 + r + lr) * K + k0 + swz, &Bs[r * 64]);
    }
    __syncthreads();

#pragma unroll
    for (int kh = 0; kh < 2; kh++) {
      const int sw = ((kh * 4 + kg) ^ (lm & 7)) << 3;
      short8 aF[2], bF[4];
#pragma unroll
      for (int i = 0; i < 2; i++)
        aF[i] = *(const short8*)&As[(wm + i * 16 + lm) * 64 + sw];
#pragma unroll
      for (int j = 0; j < 4; j++)
        bF[j] = *(const short8*)&Bs[(wn + j * 16 + lm) * 64 + sw];
#pragma unroll
      for (int i = 0; i < 2; i++)
#pragma unroll
        for (int j = 0; j < 4; j++)
          acc[i][j] = __builtin_amdgcn_mfma_f32_16x16x32_bf16(
              aF[i], bF[j], acc[i][j], 0, 0, 0);
    }
  }

  const int r4 = kg * 4;

  // ---- fused alpha epilogue (pre-activation, pre-bias projection) ----
  if constexpr (H > 0) {
    const int head = (col0 + wn) / CC;
    const int ch0 = (col0 + wn) % CC;
    float asv[4], adv[4];
#pragma unroll
    for (int j = 0; j < 4; j++) {
      asv[j] = a_s[head * CC + ch0 + j * 16 + lm];
      adv[j] = a_d[head * CC + ch0 + j * 16 + lm];
    }
    float psA[2][4], pdA[2][4];
#pragma unroll
    for (int i = 0; i < 2; i++) {
#pragma unroll
      for (int r = 0; r < 4; r++) {
        float ps = 0.f, pd = 0.f;
#pragma unroll
        for (int j = 0; j < 4; j++) {
          ps += acc[i][j][r] * asv[j];
          pd += acc[i][j][r] * adv[j];
        }
#pragma unroll
        for (int off = 1; off < 16; off <<= 1) {
          ps += __shfl_xor(ps, off, 64);
          pd += __shfl_xor(pd, off, 64);
        }
        psA[i][r] = ps;
        pdA[i][r] = pd;
      }
    }
    if constexpr (CC == 64) {
      if (lm == 0) {
#pragma unroll
        for (int i = 0; i < 2; i++)
#pragma unroll
          for (int r = 0; r < 4; r++) {
            const int row = row0 + wm + i * 16 + r4 + r;
            if (row < n) {
              alS[(size_t)row * H + head] = psA[i][r];
              alD[(size_t)row * H + head] = pdA[i][r];
            }
          }
      }
    } else {
      // CC==128: waves w and w^1 cover the same rows (wn=0/64, same wm)
      __shared__ float redS[4][32];
      __shared__ float redD[4][32];
      if (lm == 0) {
#pragma unroll
        for (int i = 0; i < 2; i++)
#pragma unroll
          for (int r = 0; r < 4; r++) {
            redS[w][i * 16 + r4 + r] = psA[i][r];
            redD[w][i * 16 + r4 + r] = pdA[i][r];
          }
      }
      __syncthreads();
      if ((w & 1) == 0 && lane < 32) {
        const int row = row0 + wm + lane;
        if (row < n) {
          const int hd = col0 / CC;
          alS[(size_t)row * H + hd] = redS[w][lane] + redS[w + 1][lane];
          alD[(size_t)row * H + hd] = redD[w][lane] + redD[w + 1][lane];
        }
      }
    }
  }

#pragma unroll
  for (int j = 0; j < 4; j++) {
    const int col = col0 + wn + j * 16 + lm;
    const float bv = bias ? bias[col] : 0.f;
#pragma unroll
    for (int i = 0; i < 2; i++) {
#pragma unroll
      for (int r = 0; r < 4; r++) {
        const int row = row0 + wm + i * 16 + r4 + r;
        if (row < n) {
          float v = acc[i][j][r] + bv;
          if (ACT == 1) v = v > 0.f ? v : 0.f;
          if (OBF)
            Cb[(size_t)row * M + col] = f2b(v);
          else
            Cf[(size_t)row * M + col] = v;
        }
      }
    }
  }
}

// ===========================================================================
// Fused MLP + GAT1 projection, staged, 64-row tile, WITH CSR-scatter
// prologue (pos = rowptr[d] + Cpref[q][d] + rank[i], zero atomics).
// ===========================================================================
__global__ __launch_bounds__(256) void mlp_g1_kernel(
    const unsigned short* __restrict__ X, const unsigned short* __restrict__ W1t,
    const float* __restrict__ b1, const unsigned short* __restrict__ W2t,
    const float* __restrict__ b2, const unsigned short* __restrict__ G1Wt,
    const float* __restrict__ a_s, const float* __restrict__ a_d,
    float* __restrict__ alS, float* __restrict__ alD,
    unsigned short* __restrict__ Pb,
    const int* __restrict__ esrc, const int* __restrict__ edst,
    const int* __restrict__ rank, const int* __restrict__ rowptr,
    const int* __restrict__ Cpref, int* __restrict__ csr_src, int E, int n) {
  __shared__ unsigned short As[64 * 64];
  __shared__ unsigned short Bs[128 * 64];
  __shared__ unsigned short H1s[64 * 136];

  const int tid = threadIdx.x;
  const int w = tid >> 6, lane = tid & 63;
  const int row0 = blockIdx.x * 64;
  const int lr = lane >> 3, lg = lane & 7;
  const int lm = lane & 15, kg = lane >> 4;
  const int wm = (w >> 1) * 32, wn = (w & 1) * 64;
  const int swz = (lg ^ lr) << 3;
  const int r4 = kg * 4;

  // ---- prologue: atomic-free CSR scatter ----
  {
    const int tot = E + n;
    const int CS = (tot + QC - 1) / QC;
    const int gsz = (int)gridDim.x * 256;
    for (int i = (int)blockIdx.x * 256 + tid; i < tot; i += gsz) {
      int s, d;
      if (i < E) {
        s = __builtin_nontemporal_load(esrc + i);
        d = __builtin_nontemporal_load(edst + i);
      } else {
        s = d = i - E;
      }
      if ((unsigned)d < (unsigned)n && (unsigned)s < (unsigned)n) {
        const int q = i / CS;
        const int pos = rowptr[d] + Cpref[(size_t)q * n + d] +
                        __builtin_nontemporal_load(rank + i);
        __builtin_nontemporal_store(s, csr_src + pos);
      }
    }
  }

  f32x4 acc[2][4];
#pragma unroll
  for (int i = 0; i < 2; i++)
#pragma unroll
    for (int j = 0; j < 4; j++) acc[i][j] = {0.f, 0.f, 0.f, 0.f};

  // ---- phase A: h1 = relu(x @ W1t^T + b1), K=256, M=128 ----
  for (int k0 = 0; k0 < 256; k0 += 64) {
    __syncthreads();
#pragma unroll
    for (int it = 0; it < 2; it++) {
      const int r = w * 16 + it * 8;
      glds16(X + (size_t)(row0 + r + lr) * 256 + k0 + swz, &As[r * 64]);
    }
#pragma unroll
    for (int it = 0; it < 4; it++) {
      const int r = w * 32 + it * 8;
      glds16(W1t + (size_t)(r + lr) * 256 + k0 + swz, &Bs[r * 64]);
    }
    __syncthreads();
#pragma unroll
    for (int kh = 0; kh < 2; kh++) {
      const int sw = ((kh * 4 + kg) ^ (lm & 7)) << 3;
      short8 aF[2], bF[4];
#pragma unroll
      for (int i = 0; i < 2; i++)
        aF[i] = *(const short8*)&As[(wm + i * 16 + lm) * 64 + sw];
#pragma unroll
      for (int j = 0; j < 4; j++)
        bF[j] = *(const short8*)&Bs[(wn + j * 16 + lm) * 64 + sw];
#pragma unroll
      for (int i = 0; i < 2; i++)
#pragma unroll
        for (int j = 0; j < 4; j++)
          acc[i][j] = __builtin_amdgcn_mfma_f32_16x16x32_bf16(
              aF[i], bF[j], acc[i][j], 0, 0, 0);
    }
  }

  // epilogue A -> LDS (bias + relu, bf16)
#pragma unroll
  for (int j = 0; j < 4; j++) {
    const int col = wn + j * 16 + lm;
    const float bv = b1[col];
#pragma unroll
    for (int i = 0; i < 2; i++) {
#pragma unroll
      for (int r = 0; r < 4; r++) {
        const int lrow = wm + i * 16 + r4 + r;
        float v = acc[i][j][r] + bv;
        v = v > 0.f ? v : 0.f;
        H1s[lrow * 136 + col] = f2b(v);
      }
    }
  }
#pragma unroll
  for (int i = 0; i < 2; i++)
#pragma unroll
    for (int j = 0; j < 4; j++) acc[i][j] = {0.f, 0.f, 0.f, 0.f};
  __syncthreads();  // H1s complete before phase B reads

  // ---- phase B: h2 = relu(h1 @ W2t^T + b2), K=128, M=128 ----
  for (int k0 = 0; k0 < 128; k0 += 64) {
    __syncthreads();  // protect Bs reuse
#pragma unroll
    for (int it = 0; it < 4; it++) {
      const int r = w * 32 + it * 8;
      glds16(W2t + (size_t)(r + lr) * 128 + k0 + swz, &Bs[r * 64]);
    }
    __syncthreads();
#pragma unroll
    for (int kh = 0; kh < 2; kh++) {
      const int swB = ((kh * 4 + kg) ^ (lm & 7)) << 3;
      const int kofs = k0 + (kh * 4 + kg) * 8;
      short8 aF[2], bF[4];
#pragma unroll
      for (int i = 0; i < 2; i++)
        aF[i] = *(const short8*)&H1s[(wm + i * 16 + lm) * 136 + kofs];
#pragma unroll
      for (int j = 0; j < 4; j++)
        bF[j] = *(const short8*)&Bs[(wn + j * 16 + lm) * 64 + swB];
#pragma unroll
      for (int i = 0; i < 2; i++)
#pragma unroll
        for (int j = 0; j < 4; j++)
          acc[i][j] = __builtin_amdgcn_mfma_f32_16x16x32_bf16(
              aF[i], bF[j], acc[i][j], 0, 0, 0);
    }
  }

  // epilogue B: h2 (bias+relu, bf16) back into H1s (all reads done)
  __syncthreads();
#pragma unroll
  for (int j = 0; j < 4; j++) {
    const int col = wn + j * 16 + lm;
    const float bv = b2[col];
#pragma unroll
    for (int i = 0; i < 2; i++) {
#pragma unroll
      for (int r = 0; r < 4; r++) {
        const int lrow = wm + i * 16 + r4 + r;
        float v = acc[i][j][r] + bv;
        v = v > 0.f ? v : 0.f;
        H1s[lrow * 136 + col] = f2b(v);
      }
    }
  }
  __syncthreads();  // h2 complete before phase C reads

  // ---- phase C: P = h2 @ G1Wt^T, K=128, M=256 (2 col-halves) ----
  for (int c = 0; c < 2; c++) {
#pragma unroll
    for (int i = 0; i < 2; i++)
#pragma unroll
      for (int j = 0; j < 4; j++) acc[i][j] = {0.f, 0.f, 0.f, 0.f};

    for (int k0 = 0; k0 < 128; k0 += 64) {
      __syncthreads();  // protect Bs reuse
#pragma unroll
      for (int it = 0; it < 4; it++) {
        const int r = w * 32 + it * 8;
        glds16(G1Wt + (size_t)(c * 128 + r + lr) * 128 + k0 + swz,
               &Bs[r * 64]);
      }
      __syncthreads();
#pragma unroll
      for (int kh = 0; kh < 2; kh++) {
        const int swB = ((kh * 4 + kg) ^ (lm & 7)) << 3;
        const int kofs = k0 + (kh * 4 + kg) * 8;
        short8 aF[2], bF[4];
#pragma unroll
        for (int i = 0; i < 2; i++)
          aF[i] = *(const short8*)&H1s[(wm + i * 16 + lm) * 136 + kofs];
#pragma unroll
        for (int j = 0; j < 4; j++)
          bF[j] = *(const short8*)&Bs[(wn + j * 16 + lm) * 64 + swB];
#pragma unroll
        for (int i = 0; i < 2; i++)
#pragma unroll
          for (int j = 0; j < 4; j++)
            acc[i][j] = __builtin_amdgcn_mfma_f32_16x16x32_bf16(
                aF[i], bF[j], acc[i][j], 0, 0, 0);
      }
    }

    // GAT1 alpha epilogue: H=4, CC=64.  head = 2c + wn/64, unique writer.
    {
      const int head = c * 2 + (wn >> 6);
      float asv[4], adv[4];
#pragma unroll
      for (int j = 0; j < 4; j++) {
        asv[j] = a_s[head * 64 + j * 16 + lm];
        adv[j] = a_d[head * 64 + j * 16 + lm];
      }
#pragma unroll
      for (int i = 0; i < 2; i++) {
#pragma unroll
        for (int r = 0; r < 4; r++) {
          float ps = 0.f, pd = 0.f;
#pragma unroll
          for (int j = 0; j < 4; j++) {
            ps += acc[i][j][r] * asv[j];
            pd += acc[i][j][r] * adv[j];
          }
#pragma unroll
          for (int off = 1; off < 16; off <<= 1) {
            ps += __shfl_xor(ps, off, 64);
            pd += __shfl_xor(pd, off, 64);
          }
          if (lm == 0) {
            const int row = row0 + wm + i * 16 + r4 + r;
            if (row < n) {
              alS[(size_t)row * 4 + head] = ps;
              alD[(size_t)row * 4 + head] = pd;
            }
          }
        }
      }
    }

    // C-write -> Pb (bf16, no bias, no activation)
#pragma unroll
    for (int j = 0; j < 4; j++) {
      const int col = c * 128 + wn + j * 16 + lm;
#pragma unroll
      for (int i = 0; i < 2; i++) {
#pragma unroll
        for (int r = 0; r < 4; r++) {
          const int row = row0 + wm + i * 16 + r4 + r;
          if (row < n) Pb[(size_t)row * 256 + col] = f2b(acc[i][j][r]);
        }
      }
    }
  }
}

// ===========================================================================
// Fused head prep: convert x fp32->bf16 + 5 weight transposes.  Pure
// streaming (zero atomics).
// ===========================================================================
struct PrepArgs {
  const float* x; unsigned short* xb; long long nx;
  const float* W[5]; unsigned short* Wt[5];
  int K[5], M[5], t0[6];
};

__global__ __launch_bounds__(256) void fused_prep_kernel(PrepArgs a) {
  const int tid = threadIdx.x, bid = blockIdx.x, nb = gridDim.x;
  const long long gt = (long long)bid * 256 + tid;
  const long long gsz = (long long)nb * 256;
  __shared__ float tt[32][33];

  for (long long i = gt * 4; i < a.nx; i += gsz * 4) {
    float4 v = *(const float4*)(a.x + i);
    u16x4 u = {f2b(v.x), f2b(v.y), f2b(v.z), f2b(v.w)};
    *(u16x4*)(a.xb + i) = u;
  }
  for (int t = bid; t < a.t0[5]; t += nb) {
    int di = 0;
    while (t >= a.t0[di + 1]) di++;
    const int local = t - a.t0[di];
    const int K = a.K[di], M = a.M[di], mtiles = M / 32;
    const int mb = (local % mtiles) * 32, kb = (local / mtiles) * 32;
    const float* W = a.W[di];
    unsigned short* Wt = a.Wt[di];
    const int tx = tid & 31, ty = tid >> 5;  // 32 x 8
    __syncthreads();
#pragma unroll
    for (int i = 0; i < 4; i++)
      tt[ty + i * 8][tx] = W[(size_t)(kb + ty + i * 8) * M + mb + tx];
    __syncthreads();
#pragma unroll
    for (int i = 0; i < 4; i++)
      Wt[(size_t)(mb + ty + i * 8) * K + kb + tx] = f2b(tt[tx][ty + i * 8]);
  }
}

// ===========================================================================
// CSR build pass 1: one block per edge chunk, full-N histogram packed
// 2x16-bit per LDS word (100KB).  rank[i] = packed LDS-atomic return half;
// rank writes are DENSE and coalesced (single writer block per chunk).
// Counts per half-word < chunk size (13.3K) < 2^16 -> no carry.
// ===========================================================================
__global__ __launch_bounds__(256) void count_hist_kernel(
    const int* __restrict__ edst, int* __restrict__ rank,
    int* __restrict__ C, int E, int n) {
  __shared__ int h[HALFN];
  const int tid = threadIdx.x;
  const int q = blockIdx.x;
  const int NW = (n + 1) >> 1;

  for (int i = tid; i < NW; i += 256) h[i] = 0;
  __syncthreads();

  const int tot = E + n;
  const int CS = (tot + QC - 1) / QC;
  const int start = q * CS;
  const int end = min(start + CS, tot);
  for (int i = start + tid; i < end; i += 256) {
    int d = (i < E) ? __builtin_nontemporal_load(edst + i) : (i - E);
    if ((unsigned)d < (unsigned)n) {
      const int add = (d & 1) ? 0x10000 : 1;
      const int old = atomicAdd(&h[d >> 1], add);
      const int rk = (d & 1) ? ((old >> 16) & 0xffff) : (old & 0xffff);
      rank[i] = rk;
    }
  }
  __syncthreads();

  int* Cq = C + (size_t)q * n;
  for (int i = tid; i < NW; i += 256) {
    const int v = h[i];
    const int d0 = 2 * i;
    if (d0 + 1 < n) {
      int2 o = {v & 0xffff, (v >> 16) & 0xffff};
      *(int2*)&Cq[d0] = o;
    } else if (d0 < n) {
      Cq[d0] = v & 0xffff;
    }
  }
}

// ===========================================================================
// CSR scan chain.  deg = sum_q C[q][d]; scan_final also converts C[q][d]
// to exclusive prefix over q in place.
// ===========================================================================
__global__ __launch_bounds__(256) void block_reduce_kernel(
    const int* __restrict__ C, int* __restrict__ deg, int* __restrict__ bsum,
    int n) {
  __shared__ int s[256];
  const int t = threadIdx.x, i = blockIdx.x * 256 + t;
  int v = 0;
  if (i < n) {
#pragma unroll 8
    for (int q = 0; q < QC; q++) v += C[(size_t)q * n + i];
    deg[i] = v;
  }
  s[t] = v;
  __syncthreads();
#pragma unroll
  for (int off = 128; off; off >>= 1) {
    if (t < off) s[t] += s[t + off];
    __syncthreads();
  }
  if (t == 0) bsum[blockIdx.x] = s[0];
}

__global__ __launch_bounds__(256) void scan_bsums_kernel(int* __restrict__ bsum,
                                                         int nb) {
  __shared__ int s[256];
  const int t = threadIdx.x;
  const int v = (t < nb) ? bsum[t] : 0;
  s[t] = v;
  __syncthreads();
#pragma unroll
  for (int off = 1; off < 256; off <<= 1) {
    int a = (t >= off) ? s[t - off] : 0;
    __syncthreads();
    s[t] += a;
    __syncthreads();
  }
  if (t < nb) bsum[t] = s[t] - v;
}

__global__ __launch_bounds__(256) void scan_final_kernel(
    const int* __restrict__ deg, int* __restrict__ C,
    const int* __restrict__ bsumx, int* __restrict__ rowptr, int n) {
  __shared__ int s[256];
  const int t = threadIdx.x, i = blockIdx.x * 256 + t;
  const int v = (i < n) ? deg[i] : 0;
  s[t] = v;
  __syncthreads();
#pragma unroll
  for (int off = 1; off < 256; off <<= 1) {
    int a = (t >= off) ? s[t - off] : 0;
    __syncthreads();
    s[t] += a;
    __syncthreads();
  }
  if (i < n) {
    const int base = bsumx[blockIdx.x];
    rowptr[i] = base + s[t] - v;
    if (i == n - 1) rowptr[n] = base + s[t];
    int run = 0;
#pragma unroll 8
    for (int q = 0; q < QC; q++) {
      const int c = C[(size_t)q * n + i];
      C[(size_t)q * n + i] = run;
      run += c;
    }
  }
}

// ===========================================================================
// FUSED GAT softmax + aggregation.  Wave per dst.  AT gather roofline —
// do not touch.
// ===========================================================================
template <int H, int C, bool CONCAT, int ACT, int OBF>
__global__ __launch_bounds__(256) void gat_fused_kernel(
    const unsigned short* __restrict__ proj, const float* __restrict__ alpha_s,
    const float* __restrict__ alpha_d, const int* __restrict__ rowptr,
    const int* __restrict__ csr_src, const float* __restrict__ bias,
    void* __restrict__ out, int n) {
  constexpr int HC = H * C;
  constexpr int ROWSPAN = HC / 8;      // lanes covering one row (16 or 32)
  constexpr int EDGES = 64 / ROWSPAN;  // edges in flight (2 or 4)
  constexpr int WLANES = C / 8;        // writer lanes in mean mode

  __shared__ float exs[4][64 * H];
  __shared__ int sids[4][64];

  const int wv = threadIdx.x >> 6;
  const int wid = (blockIdx.x * blockDim.x + threadIdx.x) >> 6;
  const int lane = threadIdx.x & 63;
  if (wid >= n) return;
  const int dst = wid;
  const int eslot = lane / ROWSPAN;
  const int sl = lane % ROWSPAN;    // row slice: flat channels sl*8..sl*8+7
  const int h_lane = (sl * 8) / C;  // head owning this slice
  float* myex = &exs[wv][0];
  int* mysid = &sids[wv][0];

  float adv[H];
  loadH<H>(alpha_d + (size_t)dst * H, adv);
  const int rs = rowptr[dst], re = rowptr[dst + 1];

  float denomp[H];
#pragma unroll
  for (int h = 0; h < H; h++) denomp[h] = 0.f;
  f32x2 acc2[4];
#pragma unroll
  for (int p = 0; p < 4; p++) acc2[p] = {0.f, 0.f};

  const unsigned short* prow = proj + sl * 8;

  for (int base = rs; base < re; base += 64) {
    const int cnt = min(64, re - base);
    // phase 1: lane-parallel edge weights + src ids -> LDS
    if (lane < cnt) {
      const int s = __builtin_nontemporal_load(csr_src + base + lane);
      mysid[lane] = s;
      float as[H];
      loadH<H>(alpha_s + (size_t)s * H, as);
#pragma unroll
      for (int h = 0; h < H; h++) {
        float e = as[h] + adv[h];
        e = e > 0.f ? e : NEG_SLOPE * e;
        const float ex = __expf(e);
        denomp[h] += ex;
        myex[lane * H + h] = ex;
      }
    }
    __builtin_amdgcn_wave_barrier();
    // phase 2: subgroup-parallel accumulation, unrolled x2
    int j = eslot;
    for (; j + EDGES < cnt; j += 2 * EDGES) {
      const int s0 = mysid[j];
      const int s1 = mysid[j + EDGES];
      const float w0 = myex[j * H + h_lane];
      const float w1 = myex[(j + EDGES) * H + h_lane];
      const short8 r0 = *(const short8*)(prow + (size_t)s0 * HC);
      const short8 r1 = *(const short8*)(prow + (size_t)s1 * HC);
      accum8(acc2, r0, w0);
      accum8(acc2, r1, w1);
    }
    for (; j < cnt; j += EDGES) {
      const int s0 = mysid[j];
      const float w0 = myex[j * H + h_lane];
      const short8 r0 = *(const short8*)(prow + (size_t)s0 * HC);
      accum8(acc2, r0, w0);
    }
    __builtin_amdgcn_wave_barrier();
  }

  // unpack packed accumulators
  float acc[8];
#pragma unroll
  for (int p = 0; p < 4; p++) {
    acc[2 * p] = acc2[p].x;
    acc[2 * p + 1] = acc2[p].y;
  }

  // full-wave denom reduce; edge-slot acc reduce
#pragma unroll
  for (int off = 32; off; off >>= 1)
#pragma unroll
    for (int h = 0; h < H; h++)
      denomp[h] += __shfl_xor(denomp[h], off, 64);
#pragma unroll
  for (int off = ROWSPAN; off < 64; off <<= 1)
#pragma unroll
    for (int k = 0; k < 8; k++) acc[k] += __shfl_xor(acc[k], off, 64);

  const float inv = 1.f / (denomp[h_lane] + EPS_DEN);
  float v[8];
#pragma unroll
  for (int k = 0; k < 8; k++) v[k] = acc[k] * inv;

  if (!CONCAT && H == 2) {
#pragma unroll
    for (int k = 0; k < 8; k++) v[k] += __shfl_xor(v[k], 16, 64);
  }

  if (CONCAT) {
    if (eslot != 0) return;
    const int c0 = sl * 8;
    float vv[8];
#pragma unroll
    for (int k = 0; k < 8; k++) {
      float t = v[k] + bias[c0 + k];
      if (ACT == 1) t = t > 0.f ? t : (__expf(t) - 1.f);
      vv[k] = t;
    }
    if (OBF) {
      short8 o;
#pragma unroll
      for (int k = 0; k < 8; k++) o[k] = (short)f2b(vv[k]);
      __builtin_nontemporal_store(
          o, (short8*)((unsigned short*)out + (size_t)dst * HC + c0));
    } else {
      float* op = (float*)out + (size_t)dst * HC + c0;
      f32x4 o0 = {vv[0], vv[1], vv[2], vv[3]};
      f32x4 o1 = {vv[4], vv[5], vv[6], vv[7]};
      __builtin_nontemporal_store(o0, (f32x4*)op);
      __builtin_nontemporal_store(o1, (f32x4*)(op + 4));
    }
  } else {
    if (eslot != 0 || sl >= WLANES) return;
    const int c0 = sl * 8;
    const float invH = 1.f / (float)H;
    float vv[8];
#pragma unroll
    for (int k = 0; k < 8; k++) {
      float t = v[k] * invH + bias[c0 + k];
      if (ACT == 1) t = t > 0.f ? t : (__expf(t) - 1.f);
      vv[k] = t;
    }
    if (OBF) {
      short8 o;
#pragma unroll
      for (int k = 0; k < 8; k++) o[k] = (short)f2b(vv[k]);
      __builtin_nontemporal_store(
          o, (short8*)((unsigned short*)out + (size_t)dst * C + c0));
    } else {
      float* op = (float*)out + (size_t)dst * C + c0;
      f32x4 o0 = {vv[0], vv[1], vv[2], vv[3]};
      f32x4 o1 = {vv[4], vv[5], vv[6], vv[7]};
      __builtin_nontemporal_store(o0, (f32x4*)op);
      __builtin_nontemporal_store(o1, (f32x4*)(op + 4));
    }
  }
}

// ===========================================================================
// Host side
// ===========================================================================
extern "C" void kernel_launch(void* const* d_in, const int* in_sizes, int n_in,
                              void* d_out, int out_size, void* d_ws,
                              size_t ws_size, hipStream_t stream) {
  const float* x    = (const float*)d_in[0];
  const int*   ei   = (const int*)d_in[1];
  const float* W1   = (const float*)d_in[2];
  const float* b1   = (const float*)d_in[3];
  const float* W2   = (const float*)d_in[4];
  const float* b2   = (const float*)d_in[5];
  const float* g1W  = (const float*)d_in[6];
  const float* g1as = (const float*)d_in[7];
  const float* g1ad = (const float*)d_in[8];
  const float* g1b  = (const float*)d_in[9];
  const float* g2W  = (const float*)d_in[10];
  const float* g2as = (const float*)d_in[11];
  const float* g2ad = (const float*)d_in[12];
  const float* g2b  = (const float*)d_in[13];
  const float* g3W  = (const float*)d_in[14];
  const float* g3as = (const float*)d_in[15];
  const float* g3ad = (const float*)d_in[16];
  const float* g3b  = (const float*)d_in[17];

  const int N = in_sizes[0] / 256;   // 50000
  const int E = in_sizes[1] / 2;     // 800000
  const int Etot = E + N;
  const int NT = (N + 127) / 128;
  const int NT64 = (N + 63) / 64;
  const int NP = NT * 128;
  const int NB = (N + 255) / 256;    // scan chunks (196 <= 256)

  // ---- workspace layout ----
  char* p = (char*)d_ws;
  unsigned short* Pb  = (unsigned short*)p; p += (size_t)NP * 256 * 2;  // bf16 proj
  unsigned short* xb  = (unsigned short*)p; p += (size_t)NP * 256 * 2;  // x / act1b
  unsigned short* h2b = (unsigned short*)p; p += (size_t)NP * 128 * 2;  // act2b
  unsigned short* W1t = (unsigned short*)p; p += (size_t)128 * 256 * 2;
  unsigned short* W2t = (unsigned short*)p; p += (size_t)128 * 128 * 2;
  unsigned short* g1Wt = (unsigned short*)p; p += (size_t)256 * 128 * 2;
  unsigned short* g2Wt = (unsigned short*)p; p += (size_t)256 * 256 * 2;
  unsigned short* g3Wt = (unsigned short*)p; p += (size_t)128 * 128 * 2;
  // alpha buffers: 3 layer pairs (fully overwritten by GEMM epilogues)
  float* alB = (float*)p; p += (size_t)N * 14 * 4;
  float* alS1 = alB;
  float* alD1 = alB + (size_t)4 * N;
  float* alS2 = alB + (size_t)8 * N;
  float* alD2 = alB + (size_t)10 * N;
  float* alS3 = alB + (size_t)12 * N;
  float* alD3 = alB + (size_t)13 * N;
  int* deg    = (int*)p; p += (size_t)N * 4;
  int* rowptr = (int*)p; p += (size_t)(N + 1) * 4;
  int* bsum   = (int*)p; p += 256 * 4;
  int* rank   = (int*)p; p += (size_t)Etot * 4;
  int* Chist  = (int*)p; p += (size_t)QC * N * 4;  // per-chunk histograms
  int* csrsrc = (int*)p;

  const int* esrc = ei;
  const int* edst = ei + E;
  unsigned short* act1b = xb;   // reuse after MLP consumed xb
  unsigned short* act2b = h2b;

  // ---- CSR pass 1 (zero atomics, dense rank writes) + prep (streaming) ----
  count_hist_kernel<<<QC, 256, 0, stream>>>(edst, rank, Chist, E, N);

  PrepArgs pa;
  pa.x = x; pa.xb = xb; pa.nx = (long long)N * 256;
  pa.W[0] = W1;  pa.Wt[0] = W1t;  pa.K[0] = 256; pa.M[0] = 128;
  pa.W[1] = W2;  pa.Wt[1] = W2t;  pa.K[1] = 128; pa.M[1] = 128;
  pa.W[2] = g1W; pa.Wt[2] = g1Wt; pa.K[2] = 128; pa.M[2] = 256;
  pa.W[3] = g2W; pa.Wt[3] = g2Wt; pa.K[3] = 256; pa.M[3] = 256;
  pa.W[4] = g3W; pa.Wt[4] = g3Wt; pa.K[4] = 128; pa.M[4] = 128;
  pa.t0[0] = 0;
  for (int i = 0; i < 5; i++)
    pa.t0[i + 1] = pa.t0[i] + (pa.K[i] / 32) * (pa.M[i] / 32);
  fused_prep_kernel<<<2048, 256, 0, stream>>>(pa);

  block_reduce_kernel<<<NB, 256, 0, stream>>>(Chist, deg, bsum, N);
  scan_bsums_kernel<<<1, 256, 0, stream>>>(bsum, NB);
  scan_final_kernel<<<NB, 256, 0, stream>>>(deg, Chist, bsum, rowptr, N);

  // ---- fused MLP + GAT1 projection + alpha + CSR scatter (one kernel) ----
  mlp_g1_kernel<<<NT64, 256, 0, stream>>>(xb, W1t, b1, W2t, b2, g1Wt, g1as,
                                          g1ad, alS1, alD1, Pb, esrc, edst,
                                          rank, rowptr, Chist, csrsrc, E, N);

  // ---- GAT1 aggregation: 4 x 64, concat, ELU ----
  gat_fused_kernel<4, 64, true, 1, 1><<<(N + 3) / 4, 256, 0, stream>>>(
      Pb, alS1, alD1, rowptr, csrsrc, g1b, act1b, N);

  // ---- GAT2: 256 -> 2 x 128, mean, ELU ----
  mfma_gemm<0, 1, 2, 128><<<dim3(NT64, 2), 256, 0, stream>>>(
      act1b, g2Wt, nullptr, nullptr, Pb, g2as, g2ad, alS2, alD2, N, 256, 256);
  gat_fused_kernel<2, 128, false, 1, 1><<<(N + 3) / 4, 256, 0, stream>>>(
      Pb, alS2, alD2, rowptr, csrsrc, g2b, act2b, N);

  // ---- GAT3: 128 -> 1 x 128, mean, none -> d_out (fp32) ----
  mfma_gemm<0, 1, 1, 128><<<dim3(NT64, 1), 256, 0, stream>>>(
      act2b, g3Wt, nullptr, nullptr, Pb, g3as, g3ad, alS3, alD3, N, 128, 128);
  gat_fused_kernel<1, 128, false, 0, 0><<<(N + 3) / 4, 256, 0, stream>>>(
      Pb, alS3, alD3, rowptr, csrsrc, g3b, d_out, N);
}

// Round 13
// 421.597 us; speedup vs baseline: 1.0749x; 1.0466x over previous
//
#include <hip/hip_runtime.h>
#include <math.h>

// ---------------------------------------------------------------------------
// N=50000 nodes, E=800000 edges (+N self-loops), IN=256, HID=128, OUT=128.
// GEMMs: bf16 MFMA 16x16x32, STAGED (glds16 + XOR swizzle), 64-row x
// 128-col tiles / 4 waves (acc 2x4) — R9 measured best.
// MLP1+MLP2+GAT1proj fused in ONE kernel; CSR scatter in its prologue.
// GAT: fused softmax+aggregation — at gather roofline (3.6 TB/s), frozen.
// CSR build: single atomic count+rank pass in prep (far-atomic wall is
// unconditional: padding/replication/overlap/LDS-histogram all falsified
// R3/R5/R6/R11/R12); scatter atomic-free via rank capture.
// This is the R10 configuration (424.8 us) restored after the zero-atomic
// experiments (R11: 453, R12: 441) came back net-negative.
// ---------------------------------------------------------------------------

#define NEG_SLOPE 0.2f
#define EPS_DEN 1e-16f

typedef __attribute__((ext_vector_type(8))) short short8;
typedef __attribute__((ext_vector_type(4))) float f32x4;
typedef __attribute__((ext_vector_type(2))) float f32x2;
typedef __attribute__((ext_vector_type(4))) unsigned short u16x4;

__device__ inline unsigned short f2b(float f) {  // RNE float->bf16
  unsigned u = __builtin_bit_cast(unsigned, f);
  unsigned r = (u + 0x7fffu + ((u >> 16) & 1u)) >> 16;
  return (unsigned short)r;
}
__device__ inline float b2f(unsigned short u) {
  return __builtin_bit_cast(float, (unsigned)u << 16);
}

__device__ inline void glds16(const void* g, void* l) {
  __builtin_amdgcn_global_load_lds(
      (const __attribute__((address_space(1))) void*)g,
      (__attribute__((address_space(3))) void*)l, 16, 0, 0);
}

// packed 2xf32 fma (gfx90a+/gfx950): d = a*b + c on a VGPR pair
__device__ inline f32x2 pk_fma(f32x2 a, f32x2 b, f32x2 c) {
  f32x2 d;
  asm("v_pk_fma_f32 %0, %1, %2, %3" : "=v"(d) : "v"(a), "v"(b), "v"(c));
  return d;
}

// acc2[p] += w * bf16x8 row fragment (pairs 2p/2p+1 in lo/hi of each dword)
__device__ inline void accum8(f32x2 acc2[4], const short8 r, float w) {
  const f32x2 wv = {w, w};
  const unsigned* u = (const unsigned*)&r;
#pragma unroll
  for (int p = 0; p < 4; p++) {
    const unsigned lo = u[p] << 16;
    const unsigned hi = u[p] & 0xffff0000u;
    f32x2 val = {__builtin_bit_cast(float, lo), __builtin_bit_cast(float, hi)};
    acc2[p] = pk_fma(val, wv, acc2[p]);
  }
}

template <int H>
__device__ inline void loadH(const float* p, float* v) {
  if constexpr (H == 4) {
    float4 t = *(const float4*)p;
    v[0] = t.x; v[1] = t.y; v[2] = t.z; v[3] = t.w;
  } else if constexpr (H == 2) {
    float2 t = *(const float2*)p;
    v[0] = t.x; v[1] = t.y;
  } else {
    v[0] = *p;
  }
}

// ===========================================================================
// bf16 MFMA GEMM, staged, 64x128 tile: C[n x M] = act(A[n x K]@Bt^T + bias)
//   4 waves: wave w owns rows wm=(w>>1)*32 (+2 frags), cols wn=(w&1)*64
//   (4 frags).  acc[2][4].  glds16 staging w/ XOR swizzle, BK=64.
//   H>0: fused attention-logit epilogue, atomic-free.
// ===========================================================================
template <int ACT, int OBF, int H, int CC>
__global__ __launch_bounds__(256) void mfma_gemm(
    const unsigned short* __restrict__ A, const unsigned short* __restrict__ Bt,
    const float* __restrict__ bias, float* __restrict__ Cf,
    unsigned short* __restrict__ Cb, const float* __restrict__ a_s,
    const float* __restrict__ a_d, float* __restrict__ alS,
    float* __restrict__ alD, int n, int K, int M) {
  __shared__ unsigned short As[64 * 64];
  __shared__ unsigned short Bs[128 * 64];

  const int tid = threadIdx.x;
  const int w = tid >> 6, lane = tid & 63;
  const int row0 = blockIdx.x * 64, col0 = blockIdx.y * 128;
  const int lr = lane >> 3, lg = lane & 7;
  const int lm = lane & 15, kg = lane >> 4;
  const int wm = (w >> 1) * 32, wn = (w & 1) * 64;

  f32x4 acc[2][4];
#pragma unroll
  for (int i = 0; i < 2; i++)
#pragma unroll
    for (int j = 0; j < 4; j++) acc[i][j] = {0.f, 0.f, 0.f, 0.f};

  const int swz = (lg ^ lr) << 3;

  for (int k0 = 0; k0 < K; k0 += 64) {
    __syncthreads();
#pragma unroll
    for (int it = 0; it < 2; it++) {
      const int r = w * 16 + it * 8;
      glds16(A + (size_t)(row0 + r + lr) * K + k0 + swz, &As[r * 64]);
    }
#pragma unroll
    for (int it = 0; it < 4; it++) {
      const int r = w * 32 + it * 8;
      glds16(Bt + (size_t)(col0 + r + lr) * K + k0 + swz, &Bs[r * 64]);
    }
    __syncthreads();

#pragma unroll
    for (int kh = 0; kh < 2; kh++) {
      const int sw = ((kh * 4 + kg) ^ (lm & 7)) << 3;
      short8 aF[2], bF[4];
#pragma unroll
      for (int i = 0; i < 2; i++)
        aF[i] = *(const short8*)&As[(wm + i * 16 + lm) * 64 + sw];
#pragma unroll
      for (int j = 0; j < 4; j++)
        bF[j] = *(const short8*)&Bs[(wn + j * 16 + lm) * 64 + sw];
#pragma unroll
      for (int i = 0; i < 2; i++)
#pragma unroll
        for (int j = 0; j < 4; j++)
          acc[i][j] = __builtin_amdgcn_mfma_f32_16x16x32_bf16(
              aF[i], bF[j], acc[i][j], 0, 0, 0);
    }
  }

  const int r4 = kg * 4;

  // ---- fused alpha epilogue (pre-activation, pre-bias projection) ----
  if constexpr (H > 0) {
    const int head = (col0 + wn) / CC;
    const int ch0 = (col0 + wn) % CC;
    float asv[4], adv[4];
#pragma unroll
    for (int j = 0; j < 4; j++) {
      asv[j] = a_s[head * CC + ch0 + j * 16 + lm];
      adv[j] = a_d[head * CC + ch0 + j * 16 + lm];
    }
    float psA[2][4], pdA[2][4];
#pragma unroll
    for (int i = 0; i < 2; i++) {
#pragma unroll
      for (int r = 0; r < 4; r++) {
        float ps = 0.f, pd = 0.f;
#pragma unroll
        for (int j = 0; j < 4; j++) {
          ps += acc[i][j][r] * asv[j];
          pd += acc[i][j][r] * adv[j];
        }
#pragma unroll
        for (int off = 1; off < 16; off <<= 1) {
          ps += __shfl_xor(ps, off, 64);
          pd += __shfl_xor(pd, off, 64);
        }
        psA[i][r] = ps;
        pdA[i][r] = pd;
      }
    }
    if constexpr (CC == 64) {
      if (lm == 0) {
#pragma unroll
        for (int i = 0; i < 2; i++)
#pragma unroll
          for (int r = 0; r < 4; r++) {
            const int row = row0 + wm + i * 16 + r4 + r;
            if (row < n) {
              alS[(size_t)row * H + head] = psA[i][r];
              alD[(size_t)row * H + head] = pdA[i][r];
            }
          }
      }
    } else {
      // CC==128: waves w and w^1 cover the same rows (wn=0/64, same wm)
      __shared__ float redS[4][32];
      __shared__ float redD[4][32];
      if (lm == 0) {
#pragma unroll
        for (int i = 0; i < 2; i++)
#pragma unroll
          for (int r = 0; r < 4; r++) {
            redS[w][i * 16 + r4 + r] = psA[i][r];
            redD[w][i * 16 + r4 + r] = pdA[i][r];
          }
      }
      __syncthreads();
      if ((w & 1) == 0 && lane < 32) {
        const int row = row0 + wm + lane;
        if (row < n) {
          const int hd = col0 / CC;
          alS[(size_t)row * H + hd] = redS[w][lane] + redS[w + 1][lane];
          alD[(size_t)row * H + hd] = redD[w][lane] + redD[w + 1][lane];
        }
      }
    }
  }

#pragma unroll
  for (int j = 0; j < 4; j++) {
    const int col = col0 + wn + j * 16 + lm;
    const float bv = bias ? bias[col] : 0.f;
#pragma unroll
    for (int i = 0; i < 2; i++) {
#pragma unroll
      for (int r = 0; r < 4; r++) {
        const int row = row0 + wm + i * 16 + r4 + r;
        if (row < n) {
          float v = acc[i][j][r] + bv;
          if (ACT == 1) v = v > 0.f ? v : 0.f;
          if (OBF)
            Cb[(size_t)row * M + col] = f2b(v);
          else
            Cf[(size_t)row * M + col] = v;
        }
      }
    }
  }
}

// ===========================================================================
// Fused MLP + GAT1 projection, staged, 64-row tile, WITH CSR-scatter
// prologue (grid-stride over edges; pos = rowptr[d] + rank[i]).
//   A: h1 = relu(x @ W1t^T + b1)      K=256 -> H1s (LDS)
//   B: h2 = relu(h1 @ W2t^T + b2)     K=128 -> back into H1s
//   C: P  = h2 @ g1Wt^T (M=256, 2 col-halves) -> Pb + GAT1 alpha epilogue
// ===========================================================================
__global__ __launch_bounds__(256) void mlp_g1_kernel(
    const unsigned short* __restrict__ X, const unsigned short* __restrict__ W1t,
    const float* __restrict__ b1, const unsigned short* __restrict__ W2t,
    const float* __restrict__ b2, const unsigned short* __restrict__ G1Wt,
    const float* __restrict__ a_s, const float* __restrict__ a_d,
    float* __restrict__ alS, float* __restrict__ alD,
    unsigned short* __restrict__ Pb,
    const int* __restrict__ esrc, const int* __restrict__ edst,
    const int* __restrict__ rank, const int* __restrict__ rowptr,
    int* __restrict__ csr_src, int E, int n) {
  __shared__ unsigned short As[64 * 64];
  __shared__ unsigned short Bs[128 * 64];
  __shared__ unsigned short H1s[64 * 136];

  const int tid = threadIdx.x;
  const int w = tid >> 6, lane = tid & 63;
  const int row0 = blockIdx.x * 64;
  const int lr = lane >> 3, lg = lane & 7;
  const int lm = lane & 15, kg = lane >> 4;
  const int wm = (w >> 1) * 32, wn = (w & 1) * 64;
  const int swz = (lg ^ lr) << 3;
  const int r4 = kg * 4;

  // ---- prologue: atomic-free CSR scatter (pos = rowptr[d] + rank[i]) ----
  {
    const int tot = E + n;
    const int gsz = (int)gridDim.x * 256;
    for (int i = (int)blockIdx.x * 256 + tid; i < tot; i += gsz) {
      int s, d;
      if (i < E) {
        s = __builtin_nontemporal_load(esrc + i);
        d = __builtin_nontemporal_load(edst + i);
      } else {
        s = d = i - E;
      }
      if ((unsigned)d < (unsigned)n && (unsigned)s < (unsigned)n) {
        const int pos = rowptr[d] + __builtin_nontemporal_load(rank + i);
        __builtin_nontemporal_store(s, csr_src + pos);
      }
    }
  }

  f32x4 acc[2][4];
#pragma unroll
  for (int i = 0; i < 2; i++)
#pragma unroll
    for (int j = 0; j < 4; j++) acc[i][j] = {0.f, 0.f, 0.f, 0.f};

  // ---- phase A: h1 = relu(x @ W1t^T + b1), K=256, M=128 ----
  for (int k0 = 0; k0 < 256; k0 += 64) {
    __syncthreads();
#pragma unroll
    for (int it = 0; it < 2; it++) {
      const int r = w * 16 + it * 8;
      glds16(X + (size_t)(row0 + r + lr) * 256 + k0 + swz, &As[r * 64]);
    }
#pragma unroll
    for (int it = 0; it < 4; it++) {
      const int r = w * 32 + it * 8;
      glds16(W1t + (size_t)(r + lr) * 256 + k0 + swz, &Bs[r * 64]);
    }
    __syncthreads();
#pragma unroll
    for (int kh = 0; kh < 2; kh++) {
      const int sw = ((kh * 4 + kg) ^ (lm & 7)) << 3;
      short8 aF[2], bF[4];
#pragma unroll
      for (int i = 0; i < 2; i++)
        aF[i] = *(const short8*)&As[(wm + i * 16 + lm) * 64 + sw];
#pragma unroll
      for (int j = 0; j < 4; j++)
        bF[j] = *(const short8*)&Bs[(wn + j * 16 + lm) * 64 + sw];
#pragma unroll
      for (int i = 0; i < 2; i++)
#pragma unroll
        for (int j = 0; j < 4; j++)
          acc[i][j] = __builtin_amdgcn_mfma_f32_16x16x32_bf16(
              aF[i], bF[j], acc[i][j], 0, 0, 0);
    }
  }

  // epilogue A -> LDS (bias + relu, bf16)
#pragma unroll
  for (int j = 0; j < 4; j++) {
    const int col = wn + j * 16 + lm;
    const float bv = b1[col];
#pragma unroll
    for (int i = 0; i < 2; i++) {
#pragma unroll
      for (int r = 0; r < 4; r++) {
        const int lrow = wm + i * 16 + r4 + r;
        float v = acc[i][j][r] + bv;
        v = v > 0.f ? v : 0.f;
        H1s[lrow * 136 + col] = f2b(v);
      }
    }
  }
#pragma unroll
  for (int i = 0; i < 2; i++)
#pragma unroll
    for (int j = 0; j < 4; j++) acc[i][j] = {0.f, 0.f, 0.f, 0.f};
  __syncthreads();  // H1s complete before phase B reads

  // ---- phase B: h2 = relu(h1 @ W2t^T + b2), K=128, M=128 ----
  for (int k0 = 0; k0 < 128; k0 += 64) {
    __syncthreads();  // protect Bs reuse
#pragma unroll
    for (int it = 0; it < 4; it++) {
      const int r = w * 32 + it * 8;
      glds16(W2t + (size_t)(r + lr) * 128 + k0 + swz, &Bs[r * 64]);
    }
    __syncthreads();
#pragma unroll
    for (int kh = 0; kh < 2; kh++) {
      const int swB = ((kh * 4 + kg) ^ (lm & 7)) << 3;
      const int kofs = k0 + (kh * 4 + kg) * 8;
      short8 aF[2], bF[4];
#pragma unroll
      for (int i = 0; i < 2; i++)
        aF[i] = *(const short8*)&H1s[(wm + i * 16 + lm) * 136 + kofs];
#pragma unroll
      for (int j = 0; j < 4; j++)
        bF[j] = *(const short8*)&Bs[(wn + j * 16 + lm) * 64 + swB];
#pragma unroll
      for (int i = 0; i < 2; i++)
#pragma unroll
        for (int j = 0; j < 4; j++)
          acc[i][j] = __builtin_amdgcn_mfma_f32_16x16x32_bf16(
              aF[i], bF[j], acc[i][j], 0, 0, 0);
    }
  }

  // epilogue B: h2 (bias+relu, bf16) back into H1s (all reads done)
  __syncthreads();
#pragma unroll
  for (int j = 0; j < 4; j++) {
    const int col = wn + j * 16 + lm;
    const float bv = b2[col];
#pragma unroll
    for (int i = 0; i < 2; i++) {
#pragma unroll
      for (int r = 0; r < 4; r++) {
        const int lrow = wm + i * 16 + r4 + r;
        float v = acc[i][j][r] + bv;
        v = v > 0.f ? v : 0.f;
        H1s[lrow * 136 + col] = f2b(v);
      }
    }
  }
  __syncthreads();  // h2 complete before phase C reads

  // ---- phase C: P = h2 @ G1Wt^T, K=128, M=256 (2 col-halves) ----
  for (int c = 0; c < 2; c++) {
#pragma unroll
    for (int i = 0; i < 2; i++)
#pragma unroll
      for (int j = 0; j < 4; j++) acc[i][j] = {0.f, 0.f, 0.f, 0.f};

    for (int k0 = 0; k0 < 128; k0 += 64) {
      __syncthreads();  // protect Bs reuse
#pragma unroll
      for (int it = 0; it < 4; it++) {
        const int r = w * 32 + it * 8;
        glds16(G1Wt + (size_t)(c * 128 + r + lr) * 128 + k0 + swz,
               &Bs[r * 64]);
      }
      __syncthreads();
#pragma unroll
      for (int kh = 0; kh < 2; kh++) {
        const int swB = ((kh * 4 + kg) ^ (lm & 7)) << 3;
        const int kofs = k0 + (kh * 4 + kg) * 8;
        short8 aF[2], bF[4];
#pragma unroll
        for (int i = 0; i < 2; i++)
          aF[i] = *(const short8*)&H1s[(wm + i * 16 + lm) * 136 + kofs];
#pragma unroll
        for (int j = 0; j < 4; j++)
          bF[j] = *(const short8*)&Bs[(wn + j * 16 + lm) * 64 + swB];
#pragma unroll
        for (int i = 0; i < 2; i++)
#pragma unroll
          for (int j = 0; j < 4; j++)
            acc[i][j] = __builtin_amdgcn_mfma_f32_16x16x32_bf16(
                aF[i], bF[j], acc[i][j], 0, 0, 0);
      }
    }

    // GAT1 alpha epilogue: H=4, CC=64.  head = 2c + wn/64, unique writer.
    {
      const int head = c * 2 + (wn >> 6);
      float asv[4], adv[4];
#pragma unroll
      for (int j = 0; j < 4; j++) {
        asv[j] = a_s[head * 64 + j * 16 + lm];
        adv[j] = a_d[head * 64 + j * 16 + lm];
      }
#pragma unroll
      for (int i = 0; i < 2; i++) {
#pragma unroll
        for (int r = 0; r < 4; r++) {
          float ps = 0.f, pd = 0.f;
#pragma unroll
          for (int j = 0; j < 4; j++) {
            ps += acc[i][j][r] * asv[j];
            pd += acc[i][j][r] * adv[j];
          }
#pragma unroll
          for (int off = 1; off < 16; off <<= 1) {
            ps += __shfl_xor(ps, off, 64);
            pd += __shfl_xor(pd, off, 64);
          }
          if (lm == 0) {
            const int row = row0 + wm + i * 16 + r4 + r;
            if (row < n) {
              alS[(size_t)row * 4 + head] = ps;
              alD[(size_t)row * 4 + head] = pd;
            }
          }
        }
      }
    }

    // C-write -> Pb (bf16, no bias, no activation)
#pragma unroll
    for (int j = 0; j < 4; j++) {
      const int col = c * 128 + wn + j * 16 + lm;
#pragma unroll
      for (int i = 0; i < 2; i++) {
#pragma unroll
        for (int r = 0; r < 4; r++) {
          const int row = row0 + wm + i * 16 + r4 + r;
          if (row < n) Pb[(size_t)row * 256 + col] = f2b(acc[i][j][r]);
        }
      }
    }
  }
}

// ===========================================================================
// Fused head prep + edge counting (rank capture).  deg pre-zeroed via
// hipMemsetAsync.  2048 blocks.
// ===========================================================================
struct PrepArgs {
  const float* x; unsigned short* xb; long long nx;
  const float* W[5]; unsigned short* Wt[5];
  int K[5], M[5], t0[6];
  int* deg; int* rank; const int* edst; int E; int N;
};

__global__ __launch_bounds__(256) void fused_prep_kernel(PrepArgs a) {
  const int tid = threadIdx.x, bid = blockIdx.x, nb = gridDim.x;
  const long long gt = (long long)bid * 256 + tid;
  const long long gsz = (long long)nb * 256;
  __shared__ float tt[32][33];

  // edge counting first (start the atomic wall early)
  const long long etot = (long long)a.E + a.N;
  for (long long i = gt; i < etot; i += gsz) {
    int d = (i < a.E) ? __builtin_nontemporal_load(a.edst + i)
                      : (int)(i - a.E);
    if ((unsigned)d < (unsigned)a.N)
      a.rank[i] = atomicAdd(&a.deg[d], 1);
  }
  for (long long i = gt * 4; i < a.nx; i += gsz * 4) {
    float4 v = *(const float4*)(a.x + i);
    u16x4 u = {f2b(v.x), f2b(v.y), f2b(v.z), f2b(v.w)};
    *(u16x4*)(a.xb + i) = u;
  }
  for (int t = bid; t < a.t0[5]; t += nb) {
    int di = 0;
    while (t >= a.t0[di + 1]) di++;
    const int local = t - a.t0[di];
    const int K = a.K[di], M = a.M[di], mtiles = M / 32;
    const int mb = (local % mtiles) * 32, kb = (local / mtiles) * 32;
    const float* W = a.W[di];
    unsigned short* Wt = a.Wt[di];
    const int tx = tid & 31, ty = tid >> 5;  // 32 x 8
    __syncthreads();
#pragma unroll
    for (int i = 0; i < 4; i++)
      tt[ty + i * 8][tx] = W[(size_t)(kb + ty + i * 8) * M + mb + tx];
    __syncthreads();
#pragma unroll
    for (int i = 0; i < 4; i++)
      Wt[(size_t)(mb + ty + i * 8) * K + kb + tx] = f2b(tt[tx][ty + i * 8]);
  }
}

// ===========================================================================
// CSR scan chain (scatter lives inside mlp_g1)
// ===========================================================================
__global__ __launch_bounds__(256) void block_reduce_kernel(
    const int* __restrict__ deg, int* __restrict__ bsum, int n) {
  __shared__ int s[256];
  const int t = threadIdx.x, i = blockIdx.x * 256 + t;
  s[t] = (i < n) ? deg[i] : 0;
  __syncthreads();
#pragma unroll
  for (int off = 128; off; off >>= 1) {
    if (t < off) s[t] += s[t + off];
    __syncthreads();
  }
  if (t == 0) bsum[blockIdx.x] = s[0];
}

__global__ __launch_bounds__(256) void scan_bsums_kernel(int* __restrict__ bsum,
                                                         int nb) {
  __shared__ int s[256];
  const int t = threadIdx.x;
  const int v = (t < nb) ? bsum[t] : 0;
  s[t] = v;
  __syncthreads();
#pragma unroll
  for (int off = 1; off < 256; off <<= 1) {
    int a = (t >= off) ? s[t - off] : 0;
    __syncthreads();
    s[t] += a;
    __syncthreads();
  }
  if (t < nb) bsum[t] = s[t] - v;
}

__global__ __launch_bounds__(256) void scan_final_kernel(
    const int* __restrict__ deg, const int* __restrict__ bsumx,
    int* __restrict__ rowptr, int n) {
  __shared__ int s[256];
  const int t = threadIdx.x, i = blockIdx.x * 256 + t;
  const int v = (i < n) ? deg[i] : 0;
  s[t] = v;
  __syncthreads();
#pragma unroll
  for (int off = 1; off < 256; off <<= 1) {
    int a = (t >= off) ? s[t - off] : 0;
    __syncthreads();
    s[t] += a;
    __syncthreads();
  }
  if (i < n) {
    const int base = bsumx[blockIdx.x];
    rowptr[i] = base + s[t] - v;
    if (i == n - 1) rowptr[n] = base + s[t];
  }
}

// ===========================================================================
// FUSED GAT softmax + aggregation.  Wave per dst.  AT gather roofline —
// do not touch.
// ===========================================================================
template <int H, int C, bool CONCAT, int ACT, int OBF>
__global__ __launch_bounds__(256) void gat_fused_kernel(
    const unsigned short* __restrict__ proj, const float* __restrict__ alpha_s,
    const float* __restrict__ alpha_d, const int* __restrict__ rowptr,
    const int* __restrict__ csr_src, const float* __restrict__ bias,
    void* __restrict__ out, int n) {
  constexpr int HC = H * C;
  constexpr int ROWSPAN = HC / 8;      // lanes covering one row (16 or 32)
  constexpr int EDGES = 64 / ROWSPAN;  // edges in flight (2 or 4)
  constexpr int WLANES = C / 8;        // writer lanes in mean mode

  __shared__ float exs[4][64 * H];
  __shared__ int sids[4][64];

  const int wv = threadIdx.x >> 6;
  const int wid = (blockIdx.x * blockDim.x + threadIdx.x) >> 6;
  const int lane = threadIdx.x & 63;
  if (wid >= n) return;
  const int dst = wid;
  const int eslot = lane / ROWSPAN;
  const int sl = lane % ROWSPAN;    // row slice: flat channels sl*8..sl*8+7
  const int h_lane = (sl * 8) / C;  // head owning this slice
  float* myex = &exs[wv][0];
  int* mysid = &sids[wv][0];

  float adv[H];
  loadH<H>(alpha_d + (size_t)dst * H, adv);
  const int rs = rowptr[dst], re = rowptr[dst + 1];

  float denomp[H];
#pragma unroll
  for (int h = 0; h < H; h++) denomp[h] = 0.f;
  f32x2 acc2[4];
#pragma unroll
  for (int p = 0; p < 4; p++) acc2[p] = {0.f, 0.f};

  const unsigned short* prow = proj + sl * 8;

  for (int base = rs; base < re; base += 64) {
    const int cnt = min(64, re - base);
    // phase 1: lane-parallel edge weights + src ids -> LDS
    if (lane < cnt) {
      const int s = __builtin_nontemporal_load(csr_src + base + lane);
      mysid[lane] = s;
      float as[H];
      loadH<H>(alpha_s + (size_t)s * H, as);
#pragma unroll
      for (int h = 0; h < H; h++) {
        float e = as[h] + adv[h];
        e = e > 0.f ? e : NEG_SLOPE * e;
        const float ex = __expf(e);
        denomp[h] += ex;
        myex[lane * H + h] = ex;
      }
    }
    __builtin_amdgcn_wave_barrier();
    // phase 2: subgroup-parallel accumulation, unrolled x2
    int j = eslot;
    for (; j + EDGES < cnt; j += 2 * EDGES) {
      const int s0 = mysid[j];
      const int s1 = mysid[j + EDGES];
      const float w0 = myex[j * H + h_lane];
      const float w1 = myex[(j + EDGES) * H + h_lane];
      const short8 r0 = *(const short8*)(prow + (size_t)s0 * HC);
      const short8 r1 = *(const short8*)(prow + (size_t)s1 * HC);
      accum8(acc2, r0, w0);
      accum8(acc2, r1, w1);
    }
    for (; j < cnt; j += EDGES) {
      const int s0 = mysid[j];
      const float w0 = myex[j * H + h_lane];
      const short8 r0 = *(const short8*)(prow + (size_t)s0 * HC);
      accum8(acc2, r0, w0);
    }
    __builtin_amdgcn_wave_barrier();
  }

  // unpack packed accumulators
  float acc[8];
#pragma unroll
  for (int p = 0; p < 4; p++) {
    acc[2 * p] = acc2[p].x;
    acc[2 * p + 1] = acc2[p].y;
  }

  // full-wave denom reduce; edge-slot acc reduce
#pragma unroll
  for (int off = 32; off; off >>= 1)
#pragma unroll
    for (int h = 0; h < H; h++)
      denomp[h] += __shfl_xor(denomp[h], off, 64);
#pragma unroll
  for (int off = ROWSPAN; off < 64; off <<= 1)
#pragma unroll
    for (int k = 0; k < 8; k++) acc[k] += __shfl_xor(acc[k], off, 64);

  const float inv = 1.f / (denomp[h_lane] + EPS_DEN);
  float v[8];
#pragma unroll
  for (int k = 0; k < 8; k++) v[k] = acc[k] * inv;

  if (!CONCAT && H == 2) {
#pragma unroll
    for (int k = 0; k < 8; k++) v[k] += __shfl_xor(v[k], 16, 64);
  }

  if (CONCAT) {
    if (eslot != 0) return;
    const int c0 = sl * 8;
    float vv[8];
#pragma unroll
    for (int k = 0; k < 8; k++) {
      float t = v[k] + bias[c0 + k];
      if (ACT == 1) t = t > 0.f ? t : (__expf(t) - 1.f);
      vv[k] = t;
    }
    if (OBF) {
      short8 o;
#pragma unroll
      for (int k = 0; k < 8; k++) o[k] = (short)f2b(vv[k]);
      __builtin_nontemporal_store(
          o, (short8*)((unsigned short*)out + (size_t)dst * HC + c0));
    } else {
      float* op = (float*)out + (size_t)dst * HC + c0;
      f32x4 o0 = {vv[0], vv[1], vv[2], vv[3]};
      f32x4 o1 = {vv[4], vv[5], vv[6], vv[7]};
      __builtin_nontemporal_store(o0, (f32x4*)op);
      __builtin_nontemporal_store(o1, (f32x4*)(op + 4));
    }
  } else {
    if (eslot != 0 || sl >= WLANES) return;
    const int c0 = sl * 8;
    const float invH = 1.f / (float)H;
    float vv[8];
#pragma unroll
    for (int k = 0; k < 8; k++) {
      float t = v[k] * invH + bias[c0 + k];
      if (ACT == 1) t = t > 0.f ? t : (__expf(t) - 1.f);
      vv[k] = t;
    }
    if (OBF) {
      short8 o;
#pragma unroll
      for (int k = 0; k < 8; k++) o[k] = (short)f2b(vv[k]);
      __builtin_nontemporal_store(
          o, (short8*)((unsigned short*)out + (size_t)dst * C + c0));
    } else {
      float* op = (float*)out + (size_t)dst * C + c0;
      f32x4 o0 = {vv[0], vv[1], vv[2], vv[3]};
      f32x4 o1 = {vv[4], vv[5], vv[6], vv[7]};
      __builtin_nontemporal_store(o0, (f32x4*)op);
      __builtin_nontemporal_store(o1, (f32x4*)(op + 4));
    }
  }
}

// ===========================================================================
// Host side
// ===========================================================================
extern "C" void kernel_launch(void* const* d_in, const int* in_sizes, int n_in,
                              void* d_out, int out_size, void* d_ws,
                              size_t ws_size, hipStream_t stream) {
  const float* x    = (const float*)d_in[0];
  const int*   ei   = (const int*)d_in[1];
  const float* W1   = (const float*)d_in[2];
  const float* b1   = (const float*)d_in[3];
  const float* W2   = (const float*)d_in[4];
  const float* b2   = (const float*)d_in[5];
  const float* g1W  = (const float*)d_in[6];
  const float* g1as = (const float*)d_in[7];
  const float* g1ad = (const float*)d_in[8];
  const float* g1b  = (const float*)d_in[9];
  const float* g2W  = (const float*)d_in[10];
  const float* g2as = (const float*)d_in[11];
  const float* g2ad = (const float*)d_in[12];
  const float* g2b  = (const float*)d_in[13];
  const float* g3W  = (const float*)d_in[14];
  const float* g3as = (const float*)d_in[15];
  const float* g3ad = (const float*)d_in[16];
  const float* g3b  = (const float*)d_in[17];

  const int N = in_sizes[0] / 256;   // 50000
  const int E = in_sizes[1] / 2;     // 800000
  const int Etot = E + N;
  const int NT = (N + 127) / 128;
  const int NT64 = (N + 63) / 64;
  const int NP = NT * 128;
  const int NB = (N + 255) / 256;    // scan chunks (196 <= 256)

  // ---- workspace layout ----
  char* p = (char*)d_ws;
  unsigned short* Pb  = (unsigned short*)p; p += (size_t)NP * 256 * 2;  // bf16 proj
  unsigned short* xb  = (unsigned short*)p; p += (size_t)NP * 256 * 2;  // x / act1b
  unsigned short* h2b = (unsigned short*)p; p += (size_t)NP * 128 * 2;  // act2b
  unsigned short* W1t = (unsigned short*)p; p += (size_t)128 * 256 * 2;
  unsigned short* W2t = (unsigned short*)p; p += (size_t)128 * 128 * 2;
  unsigned short* g1Wt = (unsigned short*)p; p += (size_t)256 * 128 * 2;
  unsigned short* g2Wt = (unsigned short*)p; p += (size_t)256 * 256 * 2;
  unsigned short* g3Wt = (unsigned short*)p; p += (size_t)128 * 128 * 2;
  // alpha buffers: 3 layer pairs (fully overwritten by GEMM epilogues)
  float* alB = (float*)p; p += (size_t)N * 14 * 4;
  float* alS1 = alB;
  float* alD1 = alB + (size_t)4 * N;
  float* alS2 = alB + (size_t)8 * N;
  float* alD2 = alB + (size_t)10 * N;
  float* alS3 = alB + (size_t)12 * N;
  float* alD3 = alB + (size_t)13 * N;
  int* deg    = (int*)p; p += (size_t)N * 4;
  int* rowptr = (int*)p; p += (size_t)(N + 1) * 4;
  int* bsum   = (int*)p; p += 256 * 4;
  int* rank   = (int*)p; p += (size_t)Etot * 4;
  int* csrsrc = (int*)p;

  const int* esrc = ei;
  const int* edst = ei + E;
  unsigned short* act1b = xb;   // reuse after MLP consumed xb
  unsigned short* act2b = h2b;

  // deg must be zero before the merged prep's atomics
  hipMemsetAsync(deg, 0, (size_t)N * 4, stream);

  // ---- prep: fused head kernel (conversion + transposes + edge count) ----
  PrepArgs pa;
  pa.x = x; pa.xb = xb; pa.nx = (long long)N * 256;
  pa.W[0] = W1;  pa.Wt[0] = W1t;  pa.K[0] = 256; pa.M[0] = 128;
  pa.W[1] = W2;  pa.Wt[1] = W2t;  pa.K[1] = 128; pa.M[1] = 128;
  pa.W[2] = g1W; pa.Wt[2] = g1Wt; pa.K[2] = 128; pa.M[2] = 256;
  pa.W[3] = g2W; pa.Wt[3] = g2Wt; pa.K[3] = 256; pa.M[3] = 256;
  pa.W[4] = g3W; pa.Wt[4] = g3Wt; pa.K[4] = 128; pa.M[4] = 128;
  pa.t0[0] = 0;
  for (int i = 0; i < 5; i++)
    pa.t0[i + 1] = pa.t0[i] + (pa.K[i] / 32) * (pa.M[i] / 32);
  pa.deg = deg; pa.rank = rank; pa.edst = edst; pa.E = E; pa.N = N;
  fused_prep_kernel<<<2048, 256, 0, stream>>>(pa);

  block_reduce_kernel<<<NB, 256, 0, stream>>>(deg, bsum, N);
  scan_bsums_kernel<<<1, 256, 0, stream>>>(bsum, NB);
  scan_final_kernel<<<NB, 256, 0, stream>>>(deg, bsum, rowptr, N);

  // ---- fused MLP + GAT1 projection + alpha + CSR scatter (one kernel) ----
  mlp_g1_kernel<<<NT64, 256, 0, stream>>>(xb, W1t, b1, W2t, b2, g1Wt, g1as,
                                          g1ad, alS1, alD1, Pb, esrc, edst,
                                          rank, rowptr, csrsrc, E, N);

  // ---- GAT1 aggregation: 4 x 64, concat, ELU ----
  gat_fused_kernel<4, 64, true, 1, 1><<<(N + 3) / 4, 256, 0, stream>>>(
      Pb, alS1, alD1, rowptr, csrsrc, g1b, act1b, N);

  // ---- GAT2: 256 -> 2 x 128, mean, ELU ----
  mfma_gemm<0, 1, 2, 128><<<dim3(NT64, 2), 256, 0, stream>>>(
      act1b, g2Wt, nullptr, nullptr, Pb, g2as, g2ad, alS2, alD2, N, 256, 256);
  gat_fused_kernel<2, 128, false, 1, 1><<<(N + 3) / 4, 256, 0, stream>>>(
      Pb, alS2, alD2, rowptr, csrsrc, g2b, act2b, N);

  // ---- GAT3: 128 -> 1 x 128, mean, none -> d_out (fp32) ----
  mfma_gemm<0, 1, 1, 128><<<dim3(NT64, 1), 256, 0, stream>>>(
      act2b, g3Wt, nullptr, nullptr, Pb, g3as, g3ad, alS3, alD3, N, 128, 128);
  gat_fused_kernel<1, 128, false, 0, 0><<<(N + 3) / 4, 256, 0, stream>>>(
      Pb, alS3, alD3, rowptr, csrsrc, g3b, d_out, N);
}